// Round 18
// baseline (564.518 us; speedup 1.0000x reference)
//
#include <hip/hip_runtime.h>
#include <cstdint>
#include <cstddef>
#include <cmath>

constexpr int B = 8;
constexpr int N0 = 1024;
constexpr int CAP = 64;
using u16 = unsigned short;

typedef __bf16 bf16x8 __attribute__((ext_vector_type(8)));
typedef float f32x4 __attribute__((ext_vector_type(4)));

__device__ inline u16 f2bf(float x) {
  unsigned u = __float_as_uint(x);
  return (u16)((u + 0x7fffu + ((u >> 16) & 1u)) >> 16);
}
__device__ inline float bf2f(u16 h) { return __uint_as_float(((unsigned)h) << 16); }
__device__ inline int swk2(int row, int k) {
  int s = (((row >> 2) ^ (row >> 4)) & 3);
  return ((((k >> 3) ^ s) << 3) | (k & 7));
}

// ---------------- prep: transpose + feat0 + pooled-buffer init ----------------
__global__ __launch_bounds__(256) void k_prep(const float* __restrict__ pc,
                                              float* __restrict__ pts,
                                              float* __restrict__ feat0,
                                              uint4* __restrict__ p3, int n3,
                                              uint4* __restrict__ p6, int n6,
                                              uint4* __restrict__ p9, int n9) {
  int idx = blockIdx.x * blockDim.x + threadIdx.x;
  if (idx < B * N0) {
    int b = idx / N0, i = idx - b * N0;
    float x = pc[(b * 3 + 0) * N0 + i];
    float y = pc[(b * 3 + 1) * N0 + i];
    float z = pc[(b * 3 + 2) * N0 + i];
    pts[idx * 3 + 0] = x; pts[idx * 3 + 1] = y; pts[idx * 3 + 2] = z;
    feat0[idx * 4 + 0] = x; feat0[idx * 4 + 1] = y; feat0[idx * 4 + 2] = z; feat0[idx * 4 + 3] = 1.0f;
  }
  uint4 v = make_uint4(0xFFFFFFFFu, 0xFFFFFFFFu, 0xFFFFFFFFu, 0xFFFFFFFFu);
  for (int i = idx; i < n3; i += B * N0) p3[i] = v;
  for (int i = idx; i < n6; i += B * N0) p6[i] = v;
  for (int i = idx; i < n9; i += B * N0) p9[i] = v;
}

// ---------------- pair lists ----------------
__global__ __launch_bounds__(256) void k_pairs(const float* __restrict__ pts,
                                               int* __restrict__ pidx, int* __restrict__ pcnt,
                                               int N) {
  const int r = blockIdx.x * 4 + (threadIdx.x >> 6);
  const int lane = threadIdx.x & 63;
  const int b = r / N;
  const float px = pts[(size_t)r * 3 + 0];
  const float py = pts[(size_t)r * 3 + 1];
  const float pz = pts[(size_t)r * 3 + 2];
  int* row = pidx + (size_t)r * CAP;
  int base = 0;
  for (int j0 = 0; j0 < N; j0 += 64) {
    int j = j0 + lane;
    float dx = px - pts[((size_t)b * N + j) * 3 + 0];
    float dy = py - pts[((size_t)b * N + j) * 3 + 1];
    float dz = pz - pts[((size_t)b * N + j) * 3 + 2];
    float d2 = dx * dx + dy * dy + dz * dz;
    bool keep = d2 <= 0.1228f;
    unsigned long long mk = __ballot(keep);
    int pos = __popcll(mk & ((1ull << lane) - 1ull));
    if (keep) { int s = base + pos; if (s < CAP) row[s] = j; }
    base += __popcll(mk);
  }
  if (lane == 0) pcnt[r] = base < CAP ? base : CAP;
}

// ---------------- econtract body ----------------
__device__ __forceinline__ void econ_dev(float (*eL)[28],
                                         const float* __restrict__ pts,
                                         const float* __restrict__ feat,
                                         const int* __restrict__ pidx,
                                         const int* __restrict__ pcnt,
                                         u16* __restrict__ Shi, u16* __restrict__ Slo,
                                         int N, int Cin, int K, int Kpad, int mbase,
                                         int blockX) {
  const int g = mbase + blockX;
  const int b = g / N;
  const int t = threadIdx.x;
  const int w = t >> 6, lane = t & 63;
  const bool cact = t < Cin;
  const float px = pts[(size_t)g * 3 + 0];
  const float py = pts[(size_t)g * 3 + 1];
  const float pz = pts[(size_t)g * 3 + 2];
  float sxc = 0.f, syc = 0.f, szc = 0.f, cst = 0.f;
  if (lane < 27) {
    int a = lane / 9, bb = (lane / 3) % 3, cc = lane % 3;
    sxc = (a == 0) ? 64.f : ((a == 2) ? -64.f : 0.f);
    syc = (bb == 0) ? 64.f : ((bb == 2) ? -64.f : 0.f);
    szc = (cc == 0) ? 64.f : ((cc == 2) ? -64.f : 0.f);
    cst = -2.f * (float)((a != 1) + (bb != 1) + (cc != 1));
  }
  float acc[27];
#pragma unroll
  for (int l = 0; l < 27; ++l) acc[l] = 0.f;
  const int n = pcnt[g];
  const int* row = pidx + (size_t)g * CAP;
  for (int p = 0; p < n; ++p) {
    int j = row[p];
    size_t jb = (size_t)b * N + j;
    float dx = px - pts[jb * 3 + 0];
    float dy = py - pts[jb * 3 + 1];
    float dz = pz - pts[jb * 3 + 2];
    float d2 = dx * dx + dy * dy + dz * dz;
    if (lane < 27) {
      float ex = fmaf(-512.f, d2, fmaf(sxc, dx, fmaf(syc, dy, fmaf(szc, dz, cst))));
      eL[w][lane] = __expf(ex);
    }
    asm volatile("s_waitcnt lgkmcnt(0)" ::: "memory");
    __builtin_amdgcn_sched_barrier(0);
    float fv = cact ? feat[jb * Cin + t] : 0.f;
#pragma unroll
    for (int l = 0; l < 27; ++l) acc[l] = fmaf(eL[w][l], fv, acc[l]);
  }
  size_t rowo = (size_t)blockX * Kpad;
  if (cact) {
#pragma unroll
    for (int l = 0; l < 27; ++l) {
      float v = acc[l];
      u16 h = f2bf(v);
      u16 lo = f2bf(v - bf2f(h));
      Shi[rowo + (size_t)l * Cin + t] = h;
      Slo[rowo + (size_t)l * Cin + t] = lo;
    }
  }
  if (Kpad > K && t >= Cin && t < Cin + (Kpad - K)) {
    size_t po = rowo + K + (t - Cin);
    Shi[po] = 0; Slo[po] = 0;
  }
}

__global__ void k_econtract(const float* __restrict__ pts, const float* __restrict__ feat,
                            const int* __restrict__ pidx, const int* __restrict__ pcnt,
                            u16* __restrict__ Shi, u16* __restrict__ Slo,
                            int N, int Cin, int K, int Kpad, int mbase) {
  __shared__ float eL[4][28];
  econ_dev(eL, pts, feat, pidx, pcnt, Shi, Slo, N, Cin, K, Kpad, mbase, blockIdx.x);
}

// ---------------- FPS device code (chunked; state = d[] in global) ----------------
template <int CTRL>
__device__ __forceinline__ float dppmaxf(float v) {
  int o = __builtin_amdgcn_update_dpp(0, __float_as_int(v), CTRL, 0xF, 0xF, true);
  return fmaxf(v, __int_as_float(o));
}
__device__ __forceinline__ float wavemaxf(float v) {
  v = dppmaxf<0xB1>(v);
  v = dppmaxf<0x4E>(v);
  v = dppmaxf<0x141>(v);
  v = dppmaxf<0x140>(v);
  v = dppmaxf<0x142>(v);
  v = dppmaxf<0x143>(v);
  return __uint_as_float((unsigned)__builtin_amdgcn_readlane(__float_as_int(v), 63));
}

#define FPS_LOAD(i) \
  float qx##i = src[3 * i + 0], qy##i = src[3 * i + 1], qz##i = src[3 * i + 2];
#define FPS_PIN(i) \
  asm volatile("" : "+v"(qx##i), "+v"(qy##i), "+v"(qz##i));
#define FPS_D0A(i) \
  { float ax = __fsub_rn(qx##i, x0), ay = __fsub_rn(qy##i, y0), az = __fsub_rn(qz##i, z0); \
    d##i = __fadd_rn(__fadd_rn(__fmul_rn(ax, ax), __fmul_rn(ay, ay)), __fmul_rn(az, az)); }
#define FPS_UPD(i) \
  { float ax = __fsub_rn(qx##i, cx), ay = __fsub_rn(qy##i, cy), az = __fsub_rn(qz##i, cz); \
    float nd = __fadd_rn(__fadd_rn(__fmul_rn(ax, ax), __fmul_rn(ay, ay)), __fmul_rn(az, az)); \
    d##i = fminf(d##i, nd); }
#define FPS_SEL(i) \
  { bool e = (d##i == lbest); sx = e ? qx##i : sx; sy = e ? qy##i : sy; sz = e ? qz##i : sz; }

// fps over N=1024 (16 pts/lane), iterations [it0, it1); d-state in Dst (1024 floats)
__device__ __noinline__ void fps1024_dev(const float* __restrict__ P,
                                         float* __restrict__ centers, int m, int b, int t,
                                         int it0, int it1, float* __restrict__ Dst) {
  const float* src = P + t * 48;
  FPS_LOAD(0) FPS_LOAD(1) FPS_LOAD(2) FPS_LOAD(3)
  FPS_LOAD(4) FPS_LOAD(5) FPS_LOAD(6) FPS_LOAD(7)
  FPS_LOAD(8) FPS_LOAD(9) FPS_LOAD(10) FPS_LOAD(11)
  FPS_LOAD(12) FPS_LOAD(13) FPS_LOAD(14) FPS_LOAD(15)
  FPS_PIN(0) FPS_PIN(1) FPS_PIN(2) FPS_PIN(3)
  FPS_PIN(4) FPS_PIN(5) FPS_PIN(6) FPS_PIN(7)
  FPS_PIN(8) FPS_PIN(9) FPS_PIN(10) FPS_PIN(11)
  FPS_PIN(12) FPS_PIN(13) FPS_PIN(14) FPS_PIN(15)
  float d0, d1, d2, d3, d4, d5, d6, d7, d8, d9, d10, d11, d12, d13, d14, d15;
  if (it0 == 1) {
    float x0 = P[0], y0 = P[1], z0 = P[2];
    FPS_D0A(0) FPS_D0A(1) FPS_D0A(2) FPS_D0A(3)
    FPS_D0A(4) FPS_D0A(5) FPS_D0A(6) FPS_D0A(7)
    FPS_D0A(8) FPS_D0A(9) FPS_D0A(10) FPS_D0A(11)
    FPS_D0A(12) FPS_D0A(13) FPS_D0A(14) FPS_D0A(15)
    if (t == 0) {
      centers[(size_t)b * m * 3 + 0] = x0;
      centers[(size_t)b * m * 3 + 1] = y0;
      centers[(size_t)b * m * 3 + 2] = z0;
    }
  } else {
    const float* ds = Dst + t * 16;
    d0 = ds[0]; d1 = ds[1]; d2 = ds[2]; d3 = ds[3];
    d4 = ds[4]; d5 = ds[5]; d6 = ds[6]; d7 = ds[7];
    d8 = ds[8]; d9 = ds[9]; d10 = ds[10]; d11 = ds[11];
    d12 = ds[12]; d13 = ds[13]; d14 = ds[14]; d15 = ds[15];
  }
  for (int it = it0; it < it1; ++it) {
    float lbest;
    {
      float a0 = fmaxf(d0, d1), a1 = fmaxf(d2, d3), a2 = fmaxf(d4, d5), a3 = fmaxf(d6, d7);
      float a4 = fmaxf(d8, d9), a5 = fmaxf(d10, d11), a6 = fmaxf(d12, d13), a7 = fmaxf(d14, d15);
      float b0 = fmaxf(a0, a1), b1 = fmaxf(a2, a3), b2 = fmaxf(a4, a5), b3 = fmaxf(a6, a7);
      lbest = fmaxf(fmaxf(b0, b1), fmaxf(b2, b3));
    }
    float sx = qx15, sy = qy15, sz = qz15;
    FPS_SEL(14) FPS_SEL(13) FPS_SEL(12) FPS_SEL(11)
    FPS_SEL(10) FPS_SEL(9) FPS_SEL(8) FPS_SEL(7)
    FPS_SEL(6) FPS_SEL(5) FPS_SEL(4) FPS_SEL(3)
    FPS_SEL(2) FPS_SEL(1) FPS_SEL(0)
    float wmax = wavemaxf(lbest);
    unsigned long long mask = __ballot(lbest == wmax);
    int fl = __ffsll((long long)mask) - 1;
    float cx = __uint_as_float((unsigned)__builtin_amdgcn_readlane(__float_as_int(sx), fl));
    float cy = __uint_as_float((unsigned)__builtin_amdgcn_readlane(__float_as_int(sy), fl));
    float cz = __uint_as_float((unsigned)__builtin_amdgcn_readlane(__float_as_int(sz), fl));
    if (t == 0) {
      centers[((size_t)b * m + it) * 3 + 0] = cx;
      centers[((size_t)b * m + it) * 3 + 1] = cy;
      centers[((size_t)b * m + it) * 3 + 2] = cz;
    }
    FPS_UPD(0) FPS_UPD(1) FPS_UPD(2) FPS_UPD(3)
    FPS_UPD(4) FPS_UPD(5) FPS_UPD(6) FPS_UPD(7)
    FPS_UPD(8) FPS_UPD(9) FPS_UPD(10) FPS_UPD(11)
    FPS_UPD(12) FPS_UPD(13) FPS_UPD(14) FPS_UPD(15)
  }
  if (it1 < m) {
    float* ds = Dst + t * 16;
    ds[0] = d0; ds[1] = d1; ds[2] = d2; ds[3] = d3;
    ds[4] = d4; ds[5] = d5; ds[6] = d6; ds[7] = d7;
    ds[8] = d8; ds[9] = d9; ds[10] = d10; ds[11] = d11;
    ds[12] = d12; ds[13] = d13; ds[14] = d14; ds[15] = d15;
  }
}

// fps over N=256 (4 pts/lane)
__device__ __noinline__ void fps256_dev(const float* __restrict__ P,
                                        float* __restrict__ centers, int m, int b, int t,
                                        int it0, int it1, float* __restrict__ Dst) {
  const float* src = P + t * 12;
  FPS_LOAD(0) FPS_LOAD(1) FPS_LOAD(2) FPS_LOAD(3)
  FPS_PIN(0) FPS_PIN(1) FPS_PIN(2) FPS_PIN(3)
  float d0, d1, d2, d3;
  if (it0 == 1) {
    float x0 = P[0], y0 = P[1], z0 = P[2];
    FPS_D0A(0) FPS_D0A(1) FPS_D0A(2) FPS_D0A(3)
    if (t == 0) {
      centers[(size_t)b * m * 3 + 0] = x0;
      centers[(size_t)b * m * 3 + 1] = y0;
      centers[(size_t)b * m * 3 + 2] = z0;
    }
  } else {
    const float* ds = Dst + t * 4;
    d0 = ds[0]; d1 = ds[1]; d2 = ds[2]; d3 = ds[3];
  }
  for (int it = it0; it < it1; ++it) {
    float lbest = fmaxf(fmaxf(d0, d1), fmaxf(d2, d3));
    float sx = qx3, sy = qy3, sz = qz3;
    FPS_SEL(2) FPS_SEL(1) FPS_SEL(0)
    float wmax = wavemaxf(lbest);
    unsigned long long mask = __ballot(lbest == wmax);
    int fl = __ffsll((long long)mask) - 1;
    float cx = __uint_as_float((unsigned)__builtin_amdgcn_readlane(__float_as_int(sx), fl));
    float cy = __uint_as_float((unsigned)__builtin_amdgcn_readlane(__float_as_int(sy), fl));
    float cz = __uint_as_float((unsigned)__builtin_amdgcn_readlane(__float_as_int(sz), fl));
    if (t == 0) {
      centers[((size_t)b * m + it) * 3 + 0] = cx;
      centers[((size_t)b * m + it) * 3 + 1] = cy;
      centers[((size_t)b * m + it) * 3 + 2] = cz;
    }
    FPS_UPD(0) FPS_UPD(1) FPS_UPD(2) FPS_UPD(3)
  }
  if (it1 < m) {
    float* ds = Dst + t * 4;
    ds[0] = d0; ds[1] = d1; ds[2] = d2; ds[3] = d3;
  }
}

// ---------------- fused econtract + FPS chunk (last B blocks run FPS) ----------------
__global__ __launch_bounds__(64, 1) void k_econtract_fps(
    const float* __restrict__ pts, const float* __restrict__ feat,
    const int* __restrict__ pidx, const int* __restrict__ pcnt,
    u16* __restrict__ Shi, u16* __restrict__ Slo,
    int N, int Cin, int K, int Kpad, int mbase,
    int fpsMode, const float* __restrict__ fpsPts, float* __restrict__ fpsCenters, int fpsM,
    int it0, int it1, float* __restrict__ fpsD) {
  __shared__ float eL[4][28];
  const int nEcon = gridDim.x - B;
  if ((int)blockIdx.x >= nEcon) {
    const int b = blockIdx.x - nEcon;
    const int t = threadIdx.x;
    if (fpsMode == 1) fps1024_dev(fpsPts + (size_t)b * 1024 * 3, fpsCenters, fpsM, b, t,
                                  it0, it1, fpsD + (size_t)b * 1024);
    else fps256_dev(fpsPts + (size_t)b * 256 * 3, fpsCenters, fpsM, b, t,
                    it0, it1, fpsD + (size_t)b * 256);
    return;
  }
  econ_dev(eL, pts, feat, pidx, pcnt, Shi, Slo, N, Cin, K, Kpad, mbase, blockIdx.x);
}

// ---------------- stage 2: MFMA GEMM (+optional hosted FPS chunk in extra y-blocks) ----------------
__global__ __launch_bounds__(512) void k_gemm_mfma(const u16* __restrict__ Shi,
                                                   const u16* __restrict__ Slo,
                                                   const float* __restrict__ W,
                                                   const float* __restrict__ bias,
                                                   float* __restrict__ out,
                                                   float* __restrict__ P,
                                                   int K, int Kpad, int Cout, float scale,
                                                   int mcur, int gyReal,
                                                   int fpsMode, const float* __restrict__ fpsPts,
                                                   float* __restrict__ fpsCenters, int fpsM,
                                                   int it0, int it1, float* __restrict__ fpsD) {
  if ((int)blockIdx.y >= gyReal) {
    if (blockIdx.z == 0 && fpsMode && threadIdx.x < 64) {
      const int b = blockIdx.y - gyReal;
      const int t = threadIdx.x;
      if (fpsMode == 1) fps1024_dev(fpsPts + (size_t)b * 1024 * 3, fpsCenters, fpsM, b, t,
                                    it0, it1, fpsD + (size_t)b * 1024);
      else fps256_dev(fpsPts + (size_t)b * 256 * 3, fpsCenters, fpsM, b, t,
                      it0, it1, fpsD + (size_t)b * 256);
    }
    return;
  }
  __shared__ u16 As[2][2][32][40];
  __shared__ u16 Bs[2][2][64][40];
  __shared__ float xch[4][64][8];
  const int t = threadIdx.x;
  const int h = t >> 8;
  const int tl = t & 255;
  const int nb = blockIdx.x * 64;
  const int m0 = blockIdx.y * 32;
  const int l = t & 63, w = t >> 6;
  const int ks = w >> 2, wq = w & 3;
  const int wm = (wq >> 1) * 16, wn = (wq & 1) * 32;
  const int la = l & 15, lg = l >> 4;
  const int ntiles = Kpad >> 6;
  const int KZ = gridDim.z, z = blockIdx.z;
  const int q = ntiles / KZ, r = ntiles % KZ;
  const int t0 = z * q + (z < r ? z : r);
  const int cnt = q + (z < r ? 1 : 0);
  const int ar = tl >> 3, ak = (tl & 7) * 4;
  const size_t aOff = (size_t)(m0 + ar) * Kpad + h * 32 + ak;
  const int aw = swk2(ar, ak);
  const int kp = (tl >> 4) * 2, n4 = (tl & 15) * 4;
  f32x4 acc0 = {0.f, 0.f, 0.f, 0.f}, acc1 = {0.f, 0.f, 0.f, 0.f};

  for (int kt = 0; kt < cnt; ++kt) {
    const int k0 = (t0 + kt) * 64;
    *(ushort4*)&As[h][0][ar][aw] = *(const ushort4*)(Shi + aOff + k0);
    *(ushort4*)&As[h][1][ar][aw] = *(const ushort4*)(Slo + aOff + k0);
    {
      int gk0 = k0 + h * 32 + kp;
      float4 b0 = make_float4(0.f, 0.f, 0.f, 0.f), b1 = b0;
      if (gk0 < K) b0 = *(const float4*)(W + (size_t)gk0 * Cout + nb + n4);
      if (gk0 + 1 < K) b1 = *(const float4*)(W + (size_t)(gk0 + 1) * Cout + nb + n4);
      float v0[4] = {b0.x, b0.y, b0.z, b0.w};
      float v1[4] = {b1.x, b1.y, b1.z, b1.w};
#pragma unroll
      for (int e = 0; e < 4; ++e) {
        int n = n4 + e;
        int kw = swk2(n, kp);
        u16 h0 = f2bf(v0[e]);
        u16 l0 = f2bf(v0[e] - bf2f(h0));
        u16 h1 = f2bf(v1[e]);
        u16 l1 = f2bf(v1[e] - bf2f(h1));
        *(unsigned*)&Bs[h][0][n][kw] = (unsigned)h0 | ((unsigned)h1 << 16);
        *(unsigned*)&Bs[h][1][n][kw] = (unsigned)l0 | ((unsigned)l1 << 16);
      }
    }
    __syncthreads();
    bf16x8 ah = *(const bf16x8*)&As[ks][0][wm + la][swk2(wm + la, lg * 8)];
    bf16x8 al = *(const bf16x8*)&As[ks][1][wm + la][swk2(wm + la, lg * 8)];
    bf16x8 bh0 = *(const bf16x8*)&Bs[ks][0][wn + la][swk2(wn + la, lg * 8)];
    bf16x8 bl0 = *(const bf16x8*)&Bs[ks][1][wn + la][swk2(wn + la, lg * 8)];
    bf16x8 bh1 = *(const bf16x8*)&Bs[ks][0][wn + 16 + la][swk2(wn + 16 + la, lg * 8)];
    bf16x8 bl1 = *(const bf16x8*)&Bs[ks][1][wn + 16 + la][swk2(wn + 16 + la, lg * 8)];
    acc0 = __builtin_amdgcn_mfma_f32_16x16x32_bf16(ah, bh0, acc0, 0, 0, 0);
    acc1 = __builtin_amdgcn_mfma_f32_16x16x32_bf16(ah, bh1, acc1, 0, 0, 0);
    acc0 = __builtin_amdgcn_mfma_f32_16x16x32_bf16(al, bh0, acc0, 0, 0, 0);
    acc1 = __builtin_amdgcn_mfma_f32_16x16x32_bf16(al, bh1, acc1, 0, 0, 0);
    acc0 = __builtin_amdgcn_mfma_f32_16x16x32_bf16(ah, bl0, acc0, 0, 0, 0);
    acc1 = __builtin_amdgcn_mfma_f32_16x16x32_bf16(ah, bl1, acc1, 0, 0, 0);
    __syncthreads();
  }
  if (w >= 4) {
#pragma unroll
    for (int r2 = 0; r2 < 4; ++r2) { xch[wq][l][r2] = acc0[r2]; xch[wq][l][r2 + 4] = acc1[r2]; }
  }
  __syncthreads();
  if (w < 4) {
#pragma unroll
    for (int r2 = 0; r2 < 4; ++r2) { acc0[r2] += xch[wq][l][r2]; acc1[r2] += xch[wq][l][r2 + 4]; }
    if (gridDim.z == 1) {
#pragma unroll
      for (int r2 = 0; r2 < 4; ++r2) {
        int gm = m0 + wm + lg * 4 + r2;
        int gn0 = nb + wn + la;
        out[(size_t)gm * Cout + gn0] = fmaxf(fmaf(acc0[r2], scale, bias[gn0]), 0.f);
        int gn1 = gn0 + 16;
        out[(size_t)gm * Cout + gn1] = fmaxf(fmaf(acc1[r2], scale, bias[gn1]), 0.f);
      }
    } else {
      float* Pz = P + (size_t)z * mcur * Cout;
#pragma unroll
      for (int r2 = 0; r2 < 4; ++r2) {
        int gm = m0 + wm + lg * 4 + r2;
        int gn0 = nb + wn + la;
        Pz[(size_t)gm * Cout + gn0] = acc0[r2];
        Pz[(size_t)gm * Cout + gn0 + 16] = acc1[r2];
      }
    }
  }
}

// ---------------- split-K reduce ----------------
__global__ __launch_bounds__(256) void k_reduce(const float* __restrict__ P,
                                                const float* __restrict__ bias,
                                                float* __restrict__ out,
                                                int n4, int Cout, int KZ, float scale,
                                                int stride) {
  int i = blockIdx.x * 256 + threadIdx.x;
  if (i >= n4) return;
  float4 s = *(const float4*)(P + (size_t)i * 4);
  for (int z = 1; z < KZ; ++z) {
    float4 v = *(const float4*)(P + (size_t)z * stride + (size_t)i * 4);
    s.x += v.x; s.y += v.y; s.z += v.z; s.w += v.w;
  }
  int c = (i * 4) % Cout;
  float4 bb = *(const float4*)(bias + c);
  float4 o;
  o.x = fmaxf(fmaf(s.x, scale, bb.x), 0.f);
  o.y = fmaxf(fmaf(s.y, scale, bb.y), 0.f);
  o.z = fmaxf(fmaf(s.z, scale, bb.z), 0.f);
  o.w = fmaxf(fmaf(s.w, scale, bb.w), 0.f);
  *(float4*)(out + (size_t)i * 4) = o;
}

// level-2 (m=1): center = first point; init assign=0
__global__ __launch_bounds__(64) void k_center0(const float* __restrict__ pts,
                                                float* __restrict__ centers,
                                                int* __restrict__ assign) {
  const int b = blockIdx.x, t = threadIdx.x;
  if (t < 3) centers[b * 3 + t] = pts[(size_t)b * 64 * 3 + t];
  assign[b * 64 + t] = 0;
}

// ---------------- assignment ----------------
__global__ __launch_bounds__(256) void k_assign(const float* __restrict__ pts,
                                                const float* __restrict__ centers,
                                                int* __restrict__ assign, int N, int m) {
  __shared__ float cs[256 * 3];
  const int t = threadIdx.x;
  const int idx = blockIdx.x * 256 + t;
  const int b = (blockIdx.x * 256) / N;
  for (int i = t; i < m * 3; i += 256) cs[i] = centers[(size_t)b * m * 3 + i];
  __syncthreads();
  float px = pts[(size_t)idx * 3 + 0], py = pts[(size_t)idx * 3 + 1], pz = pts[(size_t)idx * 3 + 2];
  float best = 3.4e38f; int bk = 0;
  for (int k = 0; k < m; ++k) {
    float dx = __fsub_rn(px, cs[k * 3 + 0]);
    float dy = __fsub_rn(py, cs[k * 3 + 1]);
    float dz = __fsub_rn(pz, cs[k * 3 + 2]);
    float dd = __fadd_rn(__fadd_rn(__fmul_rn(dx, dx), __fmul_rn(dy, dy)), __fmul_rn(dz, dz));
    if (dd < best) { best = dd; bk = k; }
  }
  assign[idx] = bk;
}

// segment max via int atomicMax
__global__ __launch_bounds__(256) void k_segmax(const float* __restrict__ feat,
                                                const int* __restrict__ assign,
                                                float* __restrict__ pooled,
                                                int N, int m, int C) {
  int idx = blockIdx.x * blockDim.x + threadIdx.x;
  if (idx >= B * N * C) return;
  int b = idx / (N * C);
  int r = idx - b * N * C;
  int i = r / C;
  int c = r - i * C;
  int a = assign[b * N + i];
  atomicMax((int*)&pooled[((size_t)b * m + a) * C + c], __float_as_int(feat[idx]));
}

// ---------------- FC ----------------
template <int K, int COUT, bool BNR>
__global__ __launch_bounds__(256) void k_fc(const float* __restrict__ x,
                                            const float* __restrict__ w,
                                            const float* __restrict__ g,
                                            const float* __restrict__ be,
                                            float* __restrict__ out) {
  __shared__ float ys[8][33];
  int t = threadIdx.x;
  int n = t >> 5, cl = t & 31;
  int c = blockIdx.x * 32 + cl;
  float acc = 0.f;
  if (c < COUT) {
    const float* xr = x + n * K;
    float a0 = 0.f, a1 = 0.f, a2 = 0.f, a3 = 0.f;
    for (int k = 0; k < K; k += 4) {
      a0 = fmaf(xr[k + 0], w[(size_t)(k + 0) * COUT + c], a0);
      a1 = fmaf(xr[k + 1], w[(size_t)(k + 1) * COUT + c], a1);
      a2 = fmaf(xr[k + 2], w[(size_t)(k + 2) * COUT + c], a2);
      a3 = fmaf(xr[k + 3], w[(size_t)(k + 3) * COUT + c], a3);
    }
    acc = (a0 + a1) + (a2 + a3);
  }
  ys[n][cl] = acc;
  __syncthreads();
  if (c >= COUT) return;
  if (BNR) {
    float mu = 0.f;
#pragma unroll
    for (int q = 0; q < 8; ++q) mu += ys[q][cl];
    mu *= 0.125f;
    float var = 0.f;
#pragma unroll
    for (int q = 0; q < 8; ++q) { float dv = ys[q][cl] - mu; var = fmaf(dv, dv, var); }
    var *= 0.125f;
    float rs = 1.f / sqrtf(var + 1e-5f);
    float v = g[c] * (acc - mu) * rs + be[c];
    out[n * COUT + c] = fmaxf(v, 0.f);
  } else {
    out[n * COUT + c] = acc + be[c];
  }
}

// ---------------- launcher ----------------
extern "C" void kernel_launch(void* const* d_in, const int* in_sizes, int n_in,
                              void* d_out, int out_size, void* d_ws, size_t ws_size,
                              hipStream_t stream) {
  (void)in_sizes; (void)n_in; (void)out_size;
  const float* pc = (const float*)d_in[0];
  const float* Wc[6]; const float* bc[6];
  for (int l = 0; l < 6; ++l) { Wc[l] = (const float*)d_in[1 + 2 * l]; bc[l] = (const float*)d_in[2 + 2 * l]; }
  const float* w1 = (const float*)d_in[13];
  const float* g1 = (const float*)d_in[14];
  const float* be1 = (const float*)d_in[15];
  const float* w2 = (const float*)d_in[16];
  const float* g2 = (const float*)d_in[17];
  const float* be2 = (const float*)d_in[18];
  const float* w3 = (const float*)d_in[19];
  const float* b3 = (const float*)d_in[20];

  float* ws = (float*)d_ws;
  size_t o = 0;
  auto A = [&](size_t n) { size_t r = o; o += (n + 63) & ~(size_t)63; return r; };
  const size_t PTS0 = A((size_t)B * 1024 * 3);
  const size_t PTS1 = A((size_t)B * 256 * 3);
  const size_t PTS2 = A((size_t)B * 64 * 3);
  const size_t PTS3 = A((size_t)B * 3);
  const size_t F0  = A((size_t)B * 1024 * 4);
  const size_t FB1 = A((size_t)B * 1024 * 64);
  const size_t FB2 = A((size_t)B * 1024 * 64);
  const size_t FB3 = A((size_t)B * 256 * 64);
  const size_t FB4 = A((size_t)B * 256 * 128);
  const size_t FB5 = A((size_t)B * 256 * 128);
  const size_t FB6 = A((size_t)B * 64 * 128);
  const size_t FB7 = A((size_t)B * 64 * 256);
  const size_t FB8 = A((size_t)B * 64 * 1024);
  const size_t FB9 = A((size_t)B * 1024);
  const size_t ASSIGN = A((size_t)B * 1024);
  const size_t Y1 = A((size_t)8 * 512);
  const size_t Y2 = A((size_t)8 * 256);
  const size_t FPSD = A((size_t)B * 1024);
  const size_t PIDX = A((size_t)B * 1024 * CAP);
  const size_t PCNT = A((size_t)B * 1024);
  const size_t dynB = o * sizeof(float);

  int* pidx = (int*)(ws + PIDX);
  int* pcnt = (int*)(ws + PCNT);

  k_prep<<<dim3((B * N0 + 255) / 256), dim3(256), 0, stream>>>(
      pc, ws + PTS0, ws + F0,
      (uint4*)(ws + FB3), B * 256 * 64 / 4,
      (uint4*)(ws + FB6), B * 64 * 128 / 4,
      (uint4*)(ws + FB9), B * 1024 / 4);

  // fpsMode: 0 none; 1 fps1024 chunks; 2 fps256 chunks. Chunks hosted in econ (eIt0,eIt1)
  // and gemm (gIt0,gIt1) of this conv's FIRST m-chunk.
  auto conv = [&](size_t ptsOff, size_t finOff, size_t foutOff, int Npts, int Cin, int Cout,
                  const float* W, const float* bias,
                  int fpsMode, size_t fpsPtsOff, size_t fpsCtrOff, int fpsM,
                  int eIt0, int eIt1, int gIt0, int gIt1) {
    const int M = B * Npts;
    const int K = 27 * Cin;
    const int Kpad = (K + 63) & ~63;
    const size_t availB = (ws_size > dynB) ? ws_size - dynB : 0;
    size_t pResB = availB / 4;
    if (pResB > (size_t)13 << 20) pResB = (size_t)13 << 20;
    const size_t sByte = availB - pResB;
    long mc = (long)(sByte / ((size_t)Kpad * 4)) & ~31L;
    int Mc = (int)((mc < (long)M) ? mc : (long)M);
    if (Mc < 32) Mc = 32;
    u16* Shi = (u16*)((char*)d_ws + dynB);
    u16* Slo = Shi + (size_t)Mc * Kpad;
    float* P = (float*)(Shi + (size_t)2 * Mc * Kpad);
    const int mch = (M + Mc - 1) / Mc;
    const float scale = 1.f / (float)Npts;
    const int blk = (Cin <= 64) ? 64 : Cin;
    const int ntiles = Kpad >> 6;
    for (int mcb = 0; mcb < mch; ++mcb) {
      const int mb0 = mcb * Mc;
      const int mcur = ((M - mb0) < Mc) ? (M - mb0) : Mc;
      const bool host = (mcb == 0 && fpsMode != 0);
      if (host && blk == 64) {
        k_econtract_fps<<<dim3(mcur + B), dim3(64), 0, stream>>>(
            ws + ptsOff, ws + finOff, pidx, pcnt, Shi, Slo, Npts, Cin, K, Kpad, mb0,
            fpsMode, ws + fpsPtsOff, ws + fpsCtrOff, fpsM, eIt0, eIt1, ws + FPSD);
      } else {
        k_econtract<<<dim3(mcur), dim3(blk), 0, stream>>>(ws + ptsOff, ws + finOff, pidx, pcnt,
                                                          Shi, Slo, Npts, Cin, K, Kpad, mb0);
      }
      const int gx = Cout / 64, gy = mcur / 32;
      int kz = 1024 / (gx * gy);
      if (kz < 1) kz = 1;
      if (kz > ntiles) kz = ntiles;
      if (kz > 16) kz = 16;
      long pcap = (long)(pResB / ((size_t)mcur * Cout * 4));
      if ((long)kz > pcap) kz = (pcap < 1) ? 1 : (int)pcap;
      float* outp = ws + foutOff + (size_t)mb0 * Cout;
      const int gyE = host ? B : 0;
      k_gemm_mfma<<<dim3(gx, gy + gyE, kz), dim3(512), 0, stream>>>(
          Shi, Slo, W, bias, outp, P, K, Kpad, Cout, scale, mcur, gy,
          host ? fpsMode : 0, ws + fpsPtsOff, ws + fpsCtrOff, fpsM, gIt0, gIt1, ws + FPSD);
      if (kz > 1) {
        int n4 = mcur * Cout / 4;
        k_reduce<<<dim3((n4 + 255) / 256), dim3(256), 0, stream>>>(
            P, bias, outp, n4, Cout, kz, scale, mcur * Cout);
      }
    }
  };

  // ---- level 0: fps1024 (PTS0 -> PTS1, m=256) chunked across conv1/conv2 econ+gemm ----
  k_pairs<<<dim3(B * 1024 / 4), dim3(256), 0, stream>>>(ws + PTS0, pidx, pcnt, 1024);
  conv(PTS0, F0, FB1, 1024, 4, 64, Wc[0], bc[0], 1, PTS0, PTS1, 256, 1, 65, 65, 129);
  conv(PTS0, FB1, FB2, 1024, 64, 64, Wc[1], bc[1], 1, PTS0, PTS1, 256, 129, 193, 193, 256);
  k_assign<<<dim3(B * 1024 / 256), dim3(256), 0, stream>>>(ws + PTS0, ws + PTS1, (int*)(ws + ASSIGN), 1024, 256);
  k_segmax<<<dim3((B * 1024 * 64 + 255) / 256), dim3(256), 0, stream>>>(ws + FB2, (int*)(ws + ASSIGN), ws + FB3, 1024, 256, 64);
  // ---- level 1: fps256 (PTS1 -> PTS2, m=64) chunked across conv3 econ+gemm ----
  k_pairs<<<dim3(B * 256 / 4), dim3(256), 0, stream>>>(ws + PTS1, pidx, pcnt, 256);
  conv(PTS1, FB3, FB4, 256, 64, 128, Wc[2], bc[2], 2, PTS1, PTS2, 64, 1, 33, 33, 64);
  conv(PTS1, FB4, FB5, 256, 128, 128, Wc[3], bc[3], 0, 0, 0, 0, 0, 0, 0, 0);
  k_assign<<<dim3(B * 256 / 256), dim3(256), 0, stream>>>(ws + PTS1, ws + PTS2, (int*)(ws + ASSIGN), 256, 64);
  k_segmax<<<dim3((B * 256 * 128 + 255) / 256), dim3(256), 0, stream>>>(ws + FB5, (int*)(ws + ASSIGN), ws + FB6, 256, 64, 128);
  // ---- level 2 ----
  k_pairs<<<dim3(B * 64 / 4), dim3(256), 0, stream>>>(ws + PTS2, pidx, pcnt, 64);
  conv(PTS2, FB6, FB7, 64, 128, 256, Wc[4], bc[4], 0, 0, 0, 0, 0, 0, 0, 0);
  conv(PTS2, FB7, FB8, 64, 256, 1024, Wc[5], bc[5], 0, 0, 0, 0, 0, 0, 0, 0);
  k_center0<<<dim3(B), dim3(64), 0, stream>>>(ws + PTS2, ws + PTS3, (int*)(ws + ASSIGN));
  k_segmax<<<dim3((B * 64 * 1024 + 255) / 256), dim3(256), 0, stream>>>(ws + FB8, (int*)(ws + ASSIGN), ws + FB9, 64, 1, 1024);
  // ---- FC head ----
  k_fc<1024, 512, true><<<dim3(512 / 32), dim3(256), 0, stream>>>(ws + FB9, w1, g1, be1, ws + Y1);
  k_fc<512, 256, true><<<dim3(256 / 32), dim3(256), 0, stream>>>(ws + Y1, w2, g2, be2, ws + Y2);
  k_fc<256, 40, false><<<dim3(2), dim3(256), 0, stream>>>(ws + Y2, w3, nullptr, b3, (float*)d_out);
}

// Round 19
// 444.140 us; speedup vs baseline: 1.2710x; 1.2710x over previous
//
#include <hip/hip_runtime.h>
#include <cstdint>
#include <cstddef>
#include <cmath>

constexpr int B = 8;
constexpr int N0 = 1024;
constexpr int CAP = 64;
using u16 = unsigned short;

typedef __bf16 bf16x8 __attribute__((ext_vector_type(8)));
typedef float f32x4 __attribute__((ext_vector_type(4)));

__device__ inline u16 f2bf(float x) {
  unsigned u = __float_as_uint(x);
  return (u16)((u + 0x7fffu + ((u >> 16) & 1u)) >> 16);
}
__device__ inline float bf2f(u16 h) { return __uint_as_float(((unsigned)h) << 16); }
__device__ inline int swk2(int row, int k) {
  int s = (((row >> 2) ^ (row >> 4)) & 3);
  return ((((k >> 3) ^ s) << 3) | (k & 7));
}

// ---------------- prep: transpose + feat0 + pooled-buffer init ----------------
__global__ __launch_bounds__(256) void k_prep(const float* __restrict__ pc,
                                              float* __restrict__ pts,
                                              float* __restrict__ feat0,
                                              uint4* __restrict__ p3, int n3,
                                              uint4* __restrict__ p6, int n6,
                                              uint4* __restrict__ p9, int n9) {
  int idx = blockIdx.x * blockDim.x + threadIdx.x;
  if (idx < B * N0) {
    int b = idx / N0, i = idx - b * N0;
    float x = pc[(b * 3 + 0) * N0 + i];
    float y = pc[(b * 3 + 1) * N0 + i];
    float z = pc[(b * 3 + 2) * N0 + i];
    pts[idx * 3 + 0] = x; pts[idx * 3 + 1] = y; pts[idx * 3 + 2] = z;
    feat0[idx * 4 + 0] = x; feat0[idx * 4 + 1] = y; feat0[idx * 4 + 2] = z; feat0[idx * 4 + 3] = 1.0f;
  }
  uint4 v = make_uint4(0xFFFFFFFFu, 0xFFFFFFFFu, 0xFFFFFFFFu, 0xFFFFFFFFu);
  for (int i = idx; i < n3; i += B * N0) p3[i] = v;
  for (int i = idx; i < n6; i += B * N0) p6[i] = v;
  for (int i = idx; i < n9; i += B * N0) p9[i] = v;
}

// ---------------- pair lists ----------------
__global__ __launch_bounds__(256) void k_pairs(const float* __restrict__ pts,
                                               int* __restrict__ pidx, int* __restrict__ pcnt,
                                               int N) {
  const int r = blockIdx.x * 4 + (threadIdx.x >> 6);
  const int lane = threadIdx.x & 63;
  const int b = r / N;
  const float px = pts[(size_t)r * 3 + 0];
  const float py = pts[(size_t)r * 3 + 1];
  const float pz = pts[(size_t)r * 3 + 2];
  int* row = pidx + (size_t)r * CAP;
  int base = 0;
  for (int j0 = 0; j0 < N; j0 += 64) {
    int j = j0 + lane;
    float dx = px - pts[((size_t)b * N + j) * 3 + 0];
    float dy = py - pts[((size_t)b * N + j) * 3 + 1];
    float dz = pz - pts[((size_t)b * N + j) * 3 + 2];
    float d2 = dx * dx + dy * dy + dz * dz;
    bool keep = d2 <= 0.1228f;
    unsigned long long mk = __ballot(keep);
    int pos = __popcll(mk & ((1ull << lane) - 1ull));
    if (keep) { int s = base + pos; if (s < CAP) row[s] = j; }
    base += __popcll(mk);
  }
  if (lane == 0) pcnt[r] = base < CAP ? base : CAP;
}

// ---------------- econtract body ----------------
__device__ __forceinline__ void econ_dev(float (*eL)[28],
                                         const float* __restrict__ pts,
                                         const float* __restrict__ feat,
                                         const int* __restrict__ pidx,
                                         const int* __restrict__ pcnt,
                                         u16* __restrict__ Shi, u16* __restrict__ Slo,
                                         int N, int Cin, int K, int Kpad, int mbase,
                                         int blockX) {
  const int g = mbase + blockX;
  const int b = g / N;
  const int t = threadIdx.x;
  const int w = t >> 6, lane = t & 63;
  const bool cact = t < Cin;
  const float px = pts[(size_t)g * 3 + 0];
  const float py = pts[(size_t)g * 3 + 1];
  const float pz = pts[(size_t)g * 3 + 2];
  float sxc = 0.f, syc = 0.f, szc = 0.f, cst = 0.f;
  if (lane < 27) {
    int a = lane / 9, bb = (lane / 3) % 3, cc = lane % 3;
    sxc = (a == 0) ? 64.f : ((a == 2) ? -64.f : 0.f);
    syc = (bb == 0) ? 64.f : ((bb == 2) ? -64.f : 0.f);
    szc = (cc == 0) ? 64.f : ((cc == 2) ? -64.f : 0.f);
    cst = -2.f * (float)((a != 1) + (bb != 1) + (cc != 1));
  }
  float acc[27];
#pragma unroll
  for (int l = 0; l < 27; ++l) acc[l] = 0.f;
  const int n = pcnt[g];
  const int* row = pidx + (size_t)g * CAP;
  for (int p = 0; p < n; ++p) {
    int j = row[p];
    size_t jb = (size_t)b * N + j;
    float dx = px - pts[jb * 3 + 0];
    float dy = py - pts[jb * 3 + 1];
    float dz = pz - pts[jb * 3 + 2];
    float d2 = dx * dx + dy * dy + dz * dz;
    if (lane < 27) {
      float ex = fmaf(-512.f, d2, fmaf(sxc, dx, fmaf(syc, dy, fmaf(szc, dz, cst))));
      eL[w][lane] = __expf(ex);
    }
    asm volatile("s_waitcnt lgkmcnt(0)" ::: "memory");
    __builtin_amdgcn_sched_barrier(0);
    float fv = cact ? feat[jb * Cin + t] : 0.f;
#pragma unroll
    for (int l = 0; l < 27; ++l) acc[l] = fmaf(eL[w][l], fv, acc[l]);
  }
  size_t rowo = (size_t)blockX * Kpad;
  if (cact) {
#pragma unroll
    for (int l = 0; l < 27; ++l) {
      float v = acc[l];
      u16 h = f2bf(v);
      u16 lo = f2bf(v - bf2f(h));
      Shi[rowo + (size_t)l * Cin + t] = h;
      Slo[rowo + (size_t)l * Cin + t] = lo;
    }
  }
  if (Kpad > K && t >= Cin && t < Cin + (Kpad - K)) {
    size_t po = rowo + K + (t - Cin);
    Shi[po] = 0; Slo[po] = 0;
  }
}

__global__ void k_econtract(const float* __restrict__ pts, const float* __restrict__ feat,
                            const int* __restrict__ pidx, const int* __restrict__ pcnt,
                            u16* __restrict__ Shi, u16* __restrict__ Slo,
                            int N, int Cin, int K, int Kpad, int mbase) {
  __shared__ float eL[4][28];
  econ_dev(eL, pts, feat, pidx, pcnt, Shi, Slo, N, Cin, K, Kpad, mbase, blockIdx.x);
}

// ---------------- FPS device code (chunked; state = d[] in global) ----------------
template <int CTRL>
__device__ __forceinline__ float dppmaxf(float v) {
  int o = __builtin_amdgcn_update_dpp(0, __float_as_int(v), CTRL, 0xF, 0xF, true);
  return fmaxf(v, __int_as_float(o));
}
__device__ __forceinline__ float wavemaxf(float v) {
  v = dppmaxf<0xB1>(v);
  v = dppmaxf<0x4E>(v);
  v = dppmaxf<0x141>(v);
  v = dppmaxf<0x140>(v);
  v = dppmaxf<0x142>(v);
  v = dppmaxf<0x143>(v);
  return __uint_as_float((unsigned)__builtin_amdgcn_readlane(__float_as_int(v), 63));
}

#define FPS_LOAD(i) \
  float qx##i = src[3 * i + 0], qy##i = src[3 * i + 1], qz##i = src[3 * i + 2];
#define FPS_PIN(i) \
  asm volatile("" : "+v"(qx##i), "+v"(qy##i), "+v"(qz##i));
#define FPS_D0A(i) \
  { float ax = __fsub_rn(qx##i, x0), ay = __fsub_rn(qy##i, y0), az = __fsub_rn(qz##i, z0); \
    d##i = __fadd_rn(__fadd_rn(__fmul_rn(ax, ax), __fmul_rn(ay, ay)), __fmul_rn(az, az)); }
#define FPS_UPD(i) \
  { float ax = __fsub_rn(qx##i, cx), ay = __fsub_rn(qy##i, cy), az = __fsub_rn(qz##i, cz); \
    float nd = __fadd_rn(__fadd_rn(__fmul_rn(ax, ax), __fmul_rn(ay, ay)), __fmul_rn(az, az)); \
    d##i = fminf(d##i, nd); }
#define FPS_SEL(i) \
  { bool e = (d##i == lbest); sx = e ? qx##i : sx; sy = e ? qy##i : sy; sz = e ? qz##i : sz; }

// fps over N=1024 (16 pts/lane), iterations [it0, it1); d-state in Dst (1024 floats)
__device__ __noinline__ void fps1024_dev(const float* __restrict__ P,
                                         float* __restrict__ centers, int m, int b, int t,
                                         int it0, int it1, float* __restrict__ Dst) {
  const float* src = P + t * 48;
  FPS_LOAD(0) FPS_LOAD(1) FPS_LOAD(2) FPS_LOAD(3)
  FPS_LOAD(4) FPS_LOAD(5) FPS_LOAD(6) FPS_LOAD(7)
  FPS_LOAD(8) FPS_LOAD(9) FPS_LOAD(10) FPS_LOAD(11)
  FPS_LOAD(12) FPS_LOAD(13) FPS_LOAD(14) FPS_LOAD(15)
  FPS_PIN(0) FPS_PIN(1) FPS_PIN(2) FPS_PIN(3)
  FPS_PIN(4) FPS_PIN(5) FPS_PIN(6) FPS_PIN(7)
  FPS_PIN(8) FPS_PIN(9) FPS_PIN(10) FPS_PIN(11)
  FPS_PIN(12) FPS_PIN(13) FPS_PIN(14) FPS_PIN(15)
  float d0, d1, d2, d3, d4, d5, d6, d7, d8, d9, d10, d11, d12, d13, d14, d15;
  if (it0 == 1) {
    float x0 = P[0], y0 = P[1], z0 = P[2];
    FPS_D0A(0) FPS_D0A(1) FPS_D0A(2) FPS_D0A(3)
    FPS_D0A(4) FPS_D0A(5) FPS_D0A(6) FPS_D0A(7)
    FPS_D0A(8) FPS_D0A(9) FPS_D0A(10) FPS_D0A(11)
    FPS_D0A(12) FPS_D0A(13) FPS_D0A(14) FPS_D0A(15)
    if (t == 0) {
      centers[(size_t)b * m * 3 + 0] = x0;
      centers[(size_t)b * m * 3 + 1] = y0;
      centers[(size_t)b * m * 3 + 2] = z0;
    }
  } else {
    const float* ds = Dst + t * 16;
    d0 = ds[0]; d1 = ds[1]; d2 = ds[2]; d3 = ds[3];
    d4 = ds[4]; d5 = ds[5]; d6 = ds[6]; d7 = ds[7];
    d8 = ds[8]; d9 = ds[9]; d10 = ds[10]; d11 = ds[11];
    d12 = ds[12]; d13 = ds[13]; d14 = ds[14]; d15 = ds[15];
  }
  for (int it = it0; it < it1; ++it) {
    float lbest;
    {
      float a0 = fmaxf(d0, d1), a1 = fmaxf(d2, d3), a2 = fmaxf(d4, d5), a3 = fmaxf(d6, d7);
      float a4 = fmaxf(d8, d9), a5 = fmaxf(d10, d11), a6 = fmaxf(d12, d13), a7 = fmaxf(d14, d15);
      float b0 = fmaxf(a0, a1), b1 = fmaxf(a2, a3), b2 = fmaxf(a4, a5), b3 = fmaxf(a6, a7);
      lbest = fmaxf(fmaxf(b0, b1), fmaxf(b2, b3));
    }
    float sx = qx15, sy = qy15, sz = qz15;
    FPS_SEL(14) FPS_SEL(13) FPS_SEL(12) FPS_SEL(11)
    FPS_SEL(10) FPS_SEL(9) FPS_SEL(8) FPS_SEL(7)
    FPS_SEL(6) FPS_SEL(5) FPS_SEL(4) FPS_SEL(3)
    FPS_SEL(2) FPS_SEL(1) FPS_SEL(0)
    float wmax = wavemaxf(lbest);
    unsigned long long mask = __ballot(lbest == wmax);
    int fl = __ffsll((long long)mask) - 1;
    float cx = __uint_as_float((unsigned)__builtin_amdgcn_readlane(__float_as_int(sx), fl));
    float cy = __uint_as_float((unsigned)__builtin_amdgcn_readlane(__float_as_int(sy), fl));
    float cz = __uint_as_float((unsigned)__builtin_amdgcn_readlane(__float_as_int(sz), fl));
    if (t == 0) {
      centers[((size_t)b * m + it) * 3 + 0] = cx;
      centers[((size_t)b * m + it) * 3 + 1] = cy;
      centers[((size_t)b * m + it) * 3 + 2] = cz;
    }
    FPS_UPD(0) FPS_UPD(1) FPS_UPD(2) FPS_UPD(3)
    FPS_UPD(4) FPS_UPD(5) FPS_UPD(6) FPS_UPD(7)
    FPS_UPD(8) FPS_UPD(9) FPS_UPD(10) FPS_UPD(11)
    FPS_UPD(12) FPS_UPD(13) FPS_UPD(14) FPS_UPD(15)
  }
  if (it1 < m) {
    float* ds = Dst + t * 16;
    ds[0] = d0; ds[1] = d1; ds[2] = d2; ds[3] = d3;
    ds[4] = d4; ds[5] = d5; ds[6] = d6; ds[7] = d7;
    ds[8] = d8; ds[9] = d9; ds[10] = d10; ds[11] = d11;
    ds[12] = d12; ds[13] = d13; ds[14] = d14; ds[15] = d15;
  }
}

// fps over N=256 (4 pts/lane)
__device__ __noinline__ void fps256_dev(const float* __restrict__ P,
                                        float* __restrict__ centers, int m, int b, int t,
                                        int it0, int it1, float* __restrict__ Dst) {
  const float* src = P + t * 12;
  FPS_LOAD(0) FPS_LOAD(1) FPS_LOAD(2) FPS_LOAD(3)
  FPS_PIN(0) FPS_PIN(1) FPS_PIN(2) FPS_PIN(3)
  float d0, d1, d2, d3;
  if (it0 == 1) {
    float x0 = P[0], y0 = P[1], z0 = P[2];
    FPS_D0A(0) FPS_D0A(1) FPS_D0A(2) FPS_D0A(3)
    if (t == 0) {
      centers[(size_t)b * m * 3 + 0] = x0;
      centers[(size_t)b * m * 3 + 1] = y0;
      centers[(size_t)b * m * 3 + 2] = z0;
    }
  } else {
    const float* ds = Dst + t * 4;
    d0 = ds[0]; d1 = ds[1]; d2 = ds[2]; d3 = ds[3];
  }
  for (int it = it0; it < it1; ++it) {
    float lbest = fmaxf(fmaxf(d0, d1), fmaxf(d2, d3));
    float sx = qx3, sy = qy3, sz = qz3;
    FPS_SEL(2) FPS_SEL(1) FPS_SEL(0)
    float wmax = wavemaxf(lbest);
    unsigned long long mask = __ballot(lbest == wmax);
    int fl = __ffsll((long long)mask) - 1;
    float cx = __uint_as_float((unsigned)__builtin_amdgcn_readlane(__float_as_int(sx), fl));
    float cy = __uint_as_float((unsigned)__builtin_amdgcn_readlane(__float_as_int(sy), fl));
    float cz = __uint_as_float((unsigned)__builtin_amdgcn_readlane(__float_as_int(sz), fl));
    if (t == 0) {
      centers[((size_t)b * m + it) * 3 + 0] = cx;
      centers[((size_t)b * m + it) * 3 + 1] = cy;
      centers[((size_t)b * m + it) * 3 + 2] = cz;
    }
    FPS_UPD(0) FPS_UPD(1) FPS_UPD(2) FPS_UPD(3)
  }
  if (it1 < m) {
    float* ds = Dst + t * 4;
    ds[0] = d0; ds[1] = d1; ds[2] = d2; ds[3] = d3;
  }
}

// ---------------- fused econtract + FPS chunk (last B blocks run FPS) ----------------
__global__ __launch_bounds__(64, 1) void k_econtract_fps(
    const float* __restrict__ pts, const float* __restrict__ feat,
    const int* __restrict__ pidx, const int* __restrict__ pcnt,
    u16* __restrict__ Shi, u16* __restrict__ Slo,
    int N, int Cin, int K, int Kpad, int mbase,
    int fpsMode, const float* __restrict__ fpsPts, float* __restrict__ fpsCenters, int fpsM,
    int it0, int it1, float* __restrict__ fpsD) {
  __shared__ float eL[4][28];
  const int nEcon = gridDim.x - B;
  if ((int)blockIdx.x >= nEcon) {
    const int b = blockIdx.x - nEcon;
    const int t = threadIdx.x;
    if (fpsMode == 1) fps1024_dev(fpsPts + (size_t)b * 1024 * 3, fpsCenters, fpsM, b, t,
                                  it0, it1, fpsD + (size_t)b * 1024);
    else fps256_dev(fpsPts + (size_t)b * 256 * 3, fpsCenters, fpsM, b, t,
                    it0, it1, fpsD + (size_t)b * 256);
    return;
  }
  econ_dev(eL, pts, feat, pidx, pcnt, Shi, Slo, N, Cin, K, Kpad, mbase, blockIdx.x);
}

// ---------------- stage 2: MFMA GEMM (clean; no FPS hosting) ----------------
__global__ __launch_bounds__(512) void k_gemm_mfma(const u16* __restrict__ Shi,
                                                   const u16* __restrict__ Slo,
                                                   const float* __restrict__ W,
                                                   const float* __restrict__ bias,
                                                   float* __restrict__ out,
                                                   float* __restrict__ P,
                                                   int K, int Kpad, int Cout, float scale,
                                                   int mcur) {
  __shared__ u16 As[2][2][32][40];
  __shared__ u16 Bs[2][2][64][40];
  __shared__ float xch[4][64][8];
  const int t = threadIdx.x;
  const int h = t >> 8;
  const int tl = t & 255;
  const int nb = blockIdx.x * 64;
  const int m0 = blockIdx.y * 32;
  const int l = t & 63, w = t >> 6;
  const int ks = w >> 2, wq = w & 3;
  const int wm = (wq >> 1) * 16, wn = (wq & 1) * 32;
  const int la = l & 15, lg = l >> 4;
  const int ntiles = Kpad >> 6;
  const int KZ = gridDim.z, z = blockIdx.z;
  const int q = ntiles / KZ, r = ntiles % KZ;
  const int t0 = z * q + (z < r ? z : r);
  const int cnt = q + (z < r ? 1 : 0);
  const int ar = tl >> 3, ak = (tl & 7) * 4;
  const size_t aOff = (size_t)(m0 + ar) * Kpad + h * 32 + ak;
  const int aw = swk2(ar, ak);
  const int kp = (tl >> 4) * 2, n4 = (tl & 15) * 4;
  f32x4 acc0 = {0.f, 0.f, 0.f, 0.f}, acc1 = {0.f, 0.f, 0.f, 0.f};

  for (int kt = 0; kt < cnt; ++kt) {
    const int k0 = (t0 + kt) * 64;
    *(ushort4*)&As[h][0][ar][aw] = *(const ushort4*)(Shi + aOff + k0);
    *(ushort4*)&As[h][1][ar][aw] = *(const ushort4*)(Slo + aOff + k0);
    {
      int gk0 = k0 + h * 32 + kp;
      float4 b0 = make_float4(0.f, 0.f, 0.f, 0.f), b1 = b0;
      if (gk0 < K) b0 = *(const float4*)(W + (size_t)gk0 * Cout + nb + n4);
      if (gk0 + 1 < K) b1 = *(const float4*)(W + (size_t)(gk0 + 1) * Cout + nb + n4);
      float v0[4] = {b0.x, b0.y, b0.z, b0.w};
      float v1[4] = {b1.x, b1.y, b1.z, b1.w};
#pragma unroll
      for (int e = 0; e < 4; ++e) {
        int n = n4 + e;
        int kw = swk2(n, kp);
        u16 h0 = f2bf(v0[e]);
        u16 l0 = f2bf(v0[e] - bf2f(h0));
        u16 h1 = f2bf(v1[e]);
        u16 l1 = f2bf(v1[e] - bf2f(h1));
        *(unsigned*)&Bs[h][0][n][kw] = (unsigned)h0 | ((unsigned)h1 << 16);
        *(unsigned*)&Bs[h][1][n][kw] = (unsigned)l0 | ((unsigned)l1 << 16);
      }
    }
    __syncthreads();
    bf16x8 ah = *(const bf16x8*)&As[ks][0][wm + la][swk2(wm + la, lg * 8)];
    bf16x8 al = *(const bf16x8*)&As[ks][1][wm + la][swk2(wm + la, lg * 8)];
    bf16x8 bh0 = *(const bf16x8*)&Bs[ks][0][wn + la][swk2(wn + la, lg * 8)];
    bf16x8 bl0 = *(const bf16x8*)&Bs[ks][1][wn + la][swk2(wn + la, lg * 8)];
    bf16x8 bh1 = *(const bf16x8*)&Bs[ks][0][wn + 16 + la][swk2(wn + 16 + la, lg * 8)];
    bf16x8 bl1 = *(const bf16x8*)&Bs[ks][1][wn + 16 + la][swk2(wn + 16 + la, lg * 8)];
    acc0 = __builtin_amdgcn_mfma_f32_16x16x32_bf16(ah, bh0, acc0, 0, 0, 0);
    acc1 = __builtin_amdgcn_mfma_f32_16x16x32_bf16(ah, bh1, acc1, 0, 0, 0);
    acc0 = __builtin_amdgcn_mfma_f32_16x16x32_bf16(al, bh0, acc0, 0, 0, 0);
    acc1 = __builtin_amdgcn_mfma_f32_16x16x32_bf16(al, bh1, acc1, 0, 0, 0);
    acc0 = __builtin_amdgcn_mfma_f32_16x16x32_bf16(ah, bl0, acc0, 0, 0, 0);
    acc1 = __builtin_amdgcn_mfma_f32_16x16x32_bf16(ah, bl1, acc1, 0, 0, 0);
    __syncthreads();
  }
  if (w >= 4) {
#pragma unroll
    for (int r2 = 0; r2 < 4; ++r2) { xch[wq][l][r2] = acc0[r2]; xch[wq][l][r2 + 4] = acc1[r2]; }
  }
  __syncthreads();
  if (w < 4) {
#pragma unroll
    for (int r2 = 0; r2 < 4; ++r2) { acc0[r2] += xch[wq][l][r2]; acc1[r2] += xch[wq][l][r2 + 4]; }
    if (gridDim.z == 1) {
#pragma unroll
      for (int r2 = 0; r2 < 4; ++r2) {
        int gm = m0 + wm + lg * 4 + r2;
        int gn0 = nb + wn + la;
        out[(size_t)gm * Cout + gn0] = fmaxf(fmaf(acc0[r2], scale, bias[gn0]), 0.f);
        int gn1 = gn0 + 16;
        out[(size_t)gm * Cout + gn1] = fmaxf(fmaf(acc1[r2], scale, bias[gn1]), 0.f);
      }
    } else {
      float* Pz = P + (size_t)z * mcur * Cout;
#pragma unroll
      for (int r2 = 0; r2 < 4; ++r2) {
        int gm = m0 + wm + lg * 4 + r2;
        int gn0 = nb + wn + la;
        Pz[(size_t)gm * Cout + gn0] = acc0[r2];
        Pz[(size_t)gm * Cout + gn0 + 16] = acc1[r2];
      }
    }
  }
}

// ---------------- split-K reduce ----------------
__global__ __launch_bounds__(256) void k_reduce(const float* __restrict__ P,
                                                const float* __restrict__ bias,
                                                float* __restrict__ out,
                                                int n4, int Cout, int KZ, float scale,
                                                int stride) {
  int i = blockIdx.x * 256 + threadIdx.x;
  if (i >= n4) return;
  float4 s = *(const float4*)(P + (size_t)i * 4);
  for (int z = 1; z < KZ; ++z) {
    float4 v = *(const float4*)(P + (size_t)z * stride + (size_t)i * 4);
    s.x += v.x; s.y += v.y; s.z += v.z; s.w += v.w;
  }
  int c = (i * 4) % Cout;
  float4 bb = *(const float4*)(bias + c);
  float4 o;
  o.x = fmaxf(fmaf(s.x, scale, bb.x), 0.f);
  o.y = fmaxf(fmaf(s.y, scale, bb.y), 0.f);
  o.z = fmaxf(fmaf(s.z, scale, bb.z), 0.f);
  o.w = fmaxf(fmaf(s.w, scale, bb.w), 0.f);
  *(float4*)(out + (size_t)i * 4) = o;
}

// level-2 (m=1): center = first point; init assign=0
__global__ __launch_bounds__(64) void k_center0(const float* __restrict__ pts,
                                                float* __restrict__ centers,
                                                int* __restrict__ assign) {
  const int b = blockIdx.x, t = threadIdx.x;
  if (t < 3) centers[b * 3 + t] = pts[(size_t)b * 64 * 3 + t];
  assign[b * 64 + t] = 0;
}

// ---------------- assignment ----------------
__global__ __launch_bounds__(256) void k_assign(const float* __restrict__ pts,
                                                const float* __restrict__ centers,
                                                int* __restrict__ assign, int N, int m) {
  __shared__ float cs[256 * 3];
  const int t = threadIdx.x;
  const int idx = blockIdx.x * 256 + t;
  const int b = (blockIdx.x * 256) / N;
  for (int i = t; i < m * 3; i += 256) cs[i] = centers[(size_t)b * m * 3 + i];
  __syncthreads();
  float px = pts[(size_t)idx * 3 + 0], py = pts[(size_t)idx * 3 + 1], pz = pts[(size_t)idx * 3 + 2];
  float best = 3.4e38f; int bk = 0;
  for (int k = 0; k < m; ++k) {
    float dx = __fsub_rn(px, cs[k * 3 + 0]);
    float dy = __fsub_rn(py, cs[k * 3 + 1]);
    float dz = __fsub_rn(pz, cs[k * 3 + 2]);
    float dd = __fadd_rn(__fadd_rn(__fmul_rn(dx, dx), __fmul_rn(dy, dy)), __fmul_rn(dz, dz));
    if (dd < best) { best = dd; bk = k; }
  }
  assign[idx] = bk;
}

// segment max via int atomicMax
__global__ __launch_bounds__(256) void k_segmax(const float* __restrict__ feat,
                                                const int* __restrict__ assign,
                                                float* __restrict__ pooled,
                                                int N, int m, int C) {
  int idx = blockIdx.x * blockDim.x + threadIdx.x;
  if (idx >= B * N * C) return;
  int b = idx / (N * C);
  int r = idx - b * N * C;
  int i = r / C;
  int c = r - i * C;
  int a = assign[b * N + i];
  atomicMax((int*)&pooled[((size_t)b * m + a) * C + c], __float_as_int(feat[idx]));
}

// ---------------- FC ----------------
template <int K, int COUT, bool BNR>
__global__ __launch_bounds__(256) void k_fc(const float* __restrict__ x,
                                            const float* __restrict__ w,
                                            const float* __restrict__ g,
                                            const float* __restrict__ be,
                                            float* __restrict__ out) {
  __shared__ float ys[8][33];
  int t = threadIdx.x;
  int n = t >> 5, cl = t & 31;
  int c = blockIdx.x * 32 + cl;
  float acc = 0.f;
  if (c < COUT) {
    const float* xr = x + n * K;
    float a0 = 0.f, a1 = 0.f, a2 = 0.f, a3 = 0.f;
    for (int k = 0; k < K; k += 4) {
      a0 = fmaf(xr[k + 0], w[(size_t)(k + 0) * COUT + c], a0);
      a1 = fmaf(xr[k + 1], w[(size_t)(k + 1) * COUT + c], a1);
      a2 = fmaf(xr[k + 2], w[(size_t)(k + 2) * COUT + c], a2);
      a3 = fmaf(xr[k + 3], w[(size_t)(k + 3) * COUT + c], a3);
    }
    acc = (a0 + a1) + (a2 + a3);
  }
  ys[n][cl] = acc;
  __syncthreads();
  if (c >= COUT) return;
  if (BNR) {
    float mu = 0.f;
#pragma unroll
    for (int q = 0; q < 8; ++q) mu += ys[q][cl];
    mu *= 0.125f;
    float var = 0.f;
#pragma unroll
    for (int q = 0; q < 8; ++q) { float dv = ys[q][cl] - mu; var = fmaf(dv, dv, var); }
    var *= 0.125f;
    float rs = 1.f / sqrtf(var + 1e-5f);
    float v = g[c] * (acc - mu) * rs + be[c];
    out[n * COUT + c] = fmaxf(v, 0.f);
  } else {
    out[n * COUT + c] = acc + be[c];
  }
}

// ---------------- launcher ----------------
extern "C" void kernel_launch(void* const* d_in, const int* in_sizes, int n_in,
                              void* d_out, int out_size, void* d_ws, size_t ws_size,
                              hipStream_t stream) {
  (void)in_sizes; (void)n_in; (void)out_size;
  const float* pc = (const float*)d_in[0];
  const float* Wc[6]; const float* bc[6];
  for (int l = 0; l < 6; ++l) { Wc[l] = (const float*)d_in[1 + 2 * l]; bc[l] = (const float*)d_in[2 + 2 * l]; }
  const float* w1 = (const float*)d_in[13];
  const float* g1 = (const float*)d_in[14];
  const float* be1 = (const float*)d_in[15];
  const float* w2 = (const float*)d_in[16];
  const float* g2 = (const float*)d_in[17];
  const float* be2 = (const float*)d_in[18];
  const float* w3 = (const float*)d_in[19];
  const float* b3 = (const float*)d_in[20];

  float* ws = (float*)d_ws;
  size_t o = 0;
  auto A = [&](size_t n) { size_t r = o; o += (n + 63) & ~(size_t)63; return r; };
  const size_t PTS0 = A((size_t)B * 1024 * 3);
  const size_t PTS1 = A((size_t)B * 256 * 3);
  const size_t PTS2 = A((size_t)B * 64 * 3);
  const size_t PTS3 = A((size_t)B * 3);
  const size_t F0  = A((size_t)B * 1024 * 4);
  const size_t FB1 = A((size_t)B * 1024 * 64);
  const size_t FB2 = A((size_t)B * 1024 * 64);
  const size_t FB3 = A((size_t)B * 256 * 64);
  const size_t FB4 = A((size_t)B * 256 * 128);
  const size_t FB5 = A((size_t)B * 256 * 128);
  const size_t FB6 = A((size_t)B * 64 * 128);
  const size_t FB7 = A((size_t)B * 64 * 256);
  const size_t FB8 = A((size_t)B * 64 * 1024);
  const size_t FB9 = A((size_t)B * 1024);
  const size_t ASSIGN = A((size_t)B * 1024);
  const size_t Y1 = A((size_t)8 * 512);
  const size_t Y2 = A((size_t)8 * 256);
  const size_t FPSD = A((size_t)B * 1024);
  const size_t PIDX = A((size_t)B * 1024 * CAP);
  const size_t PCNT = A((size_t)B * 1024);
  const size_t dynB = o * sizeof(float);

  int* pidx = (int*)(ws + PIDX);
  int* pcnt = (int*)(ws + PCNT);

  k_prep<<<dim3((B * N0 + 255) / 256), dim3(256), 0, stream>>>(
      pc, ws + PTS0, ws + F0,
      (uint4*)(ws + FB3), B * 256 * 64 / 4,
      (uint4*)(ws + FB6), B * 64 * 128 / 4,
      (uint4*)(ws + FB9), B * 1024 / 4);

  // fpsMode: 0 none; 1 fps1024 chunk [eIt0,eIt1) in this conv's first econ; 2 fps256 chunk
  auto conv = [&](size_t ptsOff, size_t finOff, size_t foutOff, int Npts, int Cin, int Cout,
                  const float* W, const float* bias,
                  int fpsMode, size_t fpsPtsOff, size_t fpsCtrOff, int fpsM,
                  int eIt0, int eIt1) {
    const int M = B * Npts;
    const int K = 27 * Cin;
    const int Kpad = (K + 63) & ~63;
    const size_t availB = (ws_size > dynB) ? ws_size - dynB : 0;
    size_t pResB = availB / 4;
    if (pResB > (size_t)13 << 20) pResB = (size_t)13 << 20;
    const size_t sByte = availB - pResB;
    long mc = (long)(sByte / ((size_t)Kpad * 4)) & ~31L;
    int Mc = (int)((mc < (long)M) ? mc : (long)M);
    if (Mc < 32) Mc = 32;
    u16* Shi = (u16*)((char*)d_ws + dynB);
    u16* Slo = Shi + (size_t)Mc * Kpad;
    float* P = (float*)(Shi + (size_t)2 * Mc * Kpad);
    const int mch = (M + Mc - 1) / Mc;
    const float scale = 1.f / (float)Npts;
    const int blk = (Cin <= 64) ? 64 : Cin;
    const int ntiles = Kpad >> 6;
    for (int mcb = 0; mcb < mch; ++mcb) {
      const int mb0 = mcb * Mc;
      const int mcur = ((M - mb0) < Mc) ? (M - mb0) : Mc;
      if (mcb == 0 && fpsMode && blk == 64) {
        k_econtract_fps<<<dim3(mcur + B), dim3(64), 0, stream>>>(
            ws + ptsOff, ws + finOff, pidx, pcnt, Shi, Slo, Npts, Cin, K, Kpad, mb0,
            fpsMode, ws + fpsPtsOff, ws + fpsCtrOff, fpsM, eIt0, eIt1, ws + FPSD);
      } else {
        k_econtract<<<dim3(mcur), dim3(blk), 0, stream>>>(ws + ptsOff, ws + finOff, pidx, pcnt,
                                                          Shi, Slo, Npts, Cin, K, Kpad, mb0);
      }
      const int gx = Cout / 64, gy = mcur / 32;
      int kz = 1024 / (gx * gy);
      if (kz < 1) kz = 1;
      if (kz > ntiles) kz = ntiles;
      if (kz > 16) kz = 16;
      long pcap = (long)(pResB / ((size_t)mcur * Cout * 4));
      if ((long)kz > pcap) kz = (pcap < 1) ? 1 : (int)pcap;
      float* outp = ws + foutOff + (size_t)mb0 * Cout;
      k_gemm_mfma<<<dim3(gx, gy, kz), dim3(512), 0, stream>>>(
          Shi, Slo, W, bias, outp, P, K, Kpad, Cout, scale, mcur);
      if (kz > 1) {
        int n4 = mcur * Cout / 4;
        k_reduce<<<dim3((n4 + 255) / 256), dim3(256), 0, stream>>>(
            P, bias, outp, n4, Cout, kz, scale, mcur * Cout);
      }
    }
  };

  // ---- level 0: fps1024 (PTS0 -> PTS1, m=256): [1,128) in conv1-econ, [128,256) in conv2-econ ----
  k_pairs<<<dim3(B * 1024 / 4), dim3(256), 0, stream>>>(ws + PTS0, pidx, pcnt, 1024);
  conv(PTS0, F0, FB1, 1024, 4, 64, Wc[0], bc[0], 1, PTS0, PTS1, 256, 1, 128);
  conv(PTS0, FB1, FB2, 1024, 64, 64, Wc[1], bc[1], 1, PTS0, PTS1, 256, 128, 256);
  k_assign<<<dim3(B * 1024 / 256), dim3(256), 0, stream>>>(ws + PTS0, ws + PTS1, (int*)(ws + ASSIGN), 1024, 256);
  k_segmax<<<dim3((B * 1024 * 64 + 255) / 256), dim3(256), 0, stream>>>(ws + FB2, (int*)(ws + ASSIGN), ws + FB3, 1024, 256, 64);
  // ---- level 1: fps256 (PTS1 -> PTS2, m=64) whole in conv3-econ ----
  k_pairs<<<dim3(B * 256 / 4), dim3(256), 0, stream>>>(ws + PTS1, pidx, pcnt, 256);
  conv(PTS1, FB3, FB4, 256, 64, 128, Wc[2], bc[2], 2, PTS1, PTS2, 64, 1, 64);
  conv(PTS1, FB4, FB5, 256, 128, 128, Wc[3], bc[3], 0, 0, 0, 0, 0, 0);
  k_assign<<<dim3(B * 256 / 256), dim3(256), 0, stream>>>(ws + PTS1, ws + PTS2, (int*)(ws + ASSIGN), 256, 64);
  k_segmax<<<dim3((B * 256 * 128 + 255) / 256), dim3(256), 0, stream>>>(ws + FB5, (int*)(ws + ASSIGN), ws + FB6, 256, 64, 128);
  // ---- level 2 ----
  k_pairs<<<dim3(B * 64 / 4), dim3(256), 0, stream>>>(ws + PTS2, pidx, pcnt, 64);
  conv(PTS2, FB6, FB7, 64, 128, 256, Wc[4], bc[4], 0, 0, 0, 0, 0, 0);
  conv(PTS2, FB7, FB8, 64, 256, 1024, Wc[5], bc[5], 0, 0, 0, 0, 0, 0);
  k_center0<<<dim3(B), dim3(64), 0, stream>>>(ws + PTS2, ws + PTS3, (int*)(ws + ASSIGN));
  k_segmax<<<dim3((B * 64 * 1024 + 255) / 256), dim3(256), 0, stream>>>(ws + FB8, (int*)(ws + ASSIGN), ws + FB9, 64, 1, 1024);
  // ---- FC head ----
  k_fc<1024, 512, true><<<dim3(512 / 32), dim3(256), 0, stream>>>(ws + FB9, w1, g1, be1, ws + Y1);
  k_fc<512, 256, true><<<dim3(256 / 32), dim3(256), 0, stream>>>(ws + Y1, w2, g2, be2, ws + Y2);
  k_fc<256, 40, false><<<dim3(2), dim3(256), 0, stream>>>(ws + Y2, w3, nullptr, b3, (float*)d_out);
}

// Round 20
// 427.717 us; speedup vs baseline: 1.3198x; 1.0384x over previous
//
#include <hip/hip_runtime.h>
#include <cstdint>
#include <cstddef>
#include <cmath>

constexpr int B = 8;
constexpr int N0 = 1024;
constexpr int CAP = 64;
using u16 = unsigned short;

typedef __bf16 bf16x8 __attribute__((ext_vector_type(8)));
typedef float f32x4 __attribute__((ext_vector_type(4)));

__device__ inline u16 f2bf(float x) {
  unsigned u = __float_as_uint(x);
  return (u16)((u + 0x7fffu + ((u >> 16) & 1u)) >> 16);
}
__device__ inline float bf2f(u16 h) { return __uint_as_float(((unsigned)h) << 16); }
__device__ inline int swk2(int row, int k) {
  int s = (((row >> 2) ^ (row >> 4)) & 3);
  return ((((k >> 3) ^ s) << 3) | (k & 7));
}

// ---------------- prep: transpose + feat0 + pooled-buffer init ----------------
__global__ __launch_bounds__(256) void k_prep(const float* __restrict__ pc,
                                              float* __restrict__ pts,
                                              float* __restrict__ feat0,
                                              uint4* __restrict__ p3, int n3,
                                              uint4* __restrict__ p6, int n6,
                                              uint4* __restrict__ p9, int n9) {
  int idx = blockIdx.x * blockDim.x + threadIdx.x;
  if (idx < B * N0) {
    int b = idx / N0, i = idx - b * N0;
    float x = pc[(b * 3 + 0) * N0 + i];
    float y = pc[(b * 3 + 1) * N0 + i];
    float z = pc[(b * 3 + 2) * N0 + i];
    pts[idx * 3 + 0] = x; pts[idx * 3 + 1] = y; pts[idx * 3 + 2] = z;
    feat0[idx * 4 + 0] = x; feat0[idx * 4 + 1] = y; feat0[idx * 4 + 2] = z; feat0[idx * 4 + 3] = 1.0f;
  }
  uint4 v = make_uint4(0xFFFFFFFFu, 0xFFFFFFFFu, 0xFFFFFFFFu, 0xFFFFFFFFu);
  for (int i = idx; i < n3; i += B * N0) p3[i] = v;
  for (int i = idx; i < n6; i += B * N0) p6[i] = v;
  for (int i = idx; i < n9; i += B * N0) p9[i] = v;
}

// ---------------- pair lists ----------------
__global__ __launch_bounds__(256) void k_pairs(const float* __restrict__ pts,
                                               int* __restrict__ pidx, int* __restrict__ pcnt,
                                               int N) {
  const int r = blockIdx.x * 4 + (threadIdx.x >> 6);
  const int lane = threadIdx.x & 63;
  const int b = r / N;
  const float px = pts[(size_t)r * 3 + 0];
  const float py = pts[(size_t)r * 3 + 1];
  const float pz = pts[(size_t)r * 3 + 2];
  int* row = pidx + (size_t)r * CAP;
  int base = 0;
  for (int j0 = 0; j0 < N; j0 += 64) {
    int j = j0 + lane;
    float dx = px - pts[((size_t)b * N + j) * 3 + 0];
    float dy = py - pts[((size_t)b * N + j) * 3 + 1];
    float dz = pz - pts[((size_t)b * N + j) * 3 + 2];
    float d2 = dx * dx + dy * dy + dz * dz;
    bool keep = d2 <= 0.1228f;
    unsigned long long mk = __ballot(keep);
    int pos = __popcll(mk & ((1ull << lane) - 1ull));
    if (keep) { int s = base + pos; if (s < CAP) row[s] = j; }
    base += __popcll(mk);
  }
  if (lane == 0) pcnt[r] = base < CAP ? base : CAP;
}

// ---------------- econtract body ----------------
__device__ __forceinline__ void econ_dev(float (*eL)[28],
                                         const float* __restrict__ pts,
                                         const float* __restrict__ feat,
                                         const int* __restrict__ pidx,
                                         const int* __restrict__ pcnt,
                                         u16* __restrict__ Shi, u16* __restrict__ Slo,
                                         int N, int Cin, int K, int Kpad, int mbase,
                                         int blockX) {
  const int g = mbase + blockX;
  const int b = g / N;
  const int t = threadIdx.x;
  const int w = t >> 6, lane = t & 63;
  const bool cact = t < Cin;
  const float px = pts[(size_t)g * 3 + 0];
  const float py = pts[(size_t)g * 3 + 1];
  const float pz = pts[(size_t)g * 3 + 2];
  float sxc = 0.f, syc = 0.f, szc = 0.f, cst = 0.f;
  if (lane < 27) {
    int a = lane / 9, bb = (lane / 3) % 3, cc = lane % 3;
    sxc = (a == 0) ? 64.f : ((a == 2) ? -64.f : 0.f);
    syc = (bb == 0) ? 64.f : ((bb == 2) ? -64.f : 0.f);
    szc = (cc == 0) ? 64.f : ((cc == 2) ? -64.f : 0.f);
    cst = -2.f * (float)((a != 1) + (bb != 1) + (cc != 1));
  }
  float acc[27];
#pragma unroll
  for (int l = 0; l < 27; ++l) acc[l] = 0.f;
  const int n = pcnt[g];
  const int* row = pidx + (size_t)g * CAP;
  for (int p = 0; p < n; ++p) {
    int j = row[p];
    size_t jb = (size_t)b * N + j;
    float dx = px - pts[jb * 3 + 0];
    float dy = py - pts[jb * 3 + 1];
    float dz = pz - pts[jb * 3 + 2];
    float d2 = dx * dx + dy * dy + dz * dz;
    if (lane < 27) {
      float ex = fmaf(-512.f, d2, fmaf(sxc, dx, fmaf(syc, dy, fmaf(szc, dz, cst))));
      eL[w][lane] = __expf(ex);
    }
    asm volatile("s_waitcnt lgkmcnt(0)" ::: "memory");
    __builtin_amdgcn_sched_barrier(0);
    float fv = cact ? feat[jb * Cin + t] : 0.f;
#pragma unroll
    for (int l = 0; l < 27; ++l) acc[l] = fmaf(eL[w][l], fv, acc[l]);
  }
  size_t rowo = (size_t)blockX * Kpad;
  if (cact) {
#pragma unroll
    for (int l = 0; l < 27; ++l) {
      float v = acc[l];
      u16 h = f2bf(v);
      u16 lo = f2bf(v - bf2f(h));
      Shi[rowo + (size_t)l * Cin + t] = h;
      Slo[rowo + (size_t)l * Cin + t] = lo;
    }
  }
  if (Kpad > K && t >= Cin && t < Cin + (Kpad - K)) {
    size_t po = rowo + K + (t - Cin);
    Shi[po] = 0; Slo[po] = 0;
  }
}

__global__ void k_econtract(const float* __restrict__ pts, const float* __restrict__ feat,
                            const int* __restrict__ pidx, const int* __restrict__ pcnt,
                            u16* __restrict__ Shi, u16* __restrict__ Slo,
                            int N, int Cin, int K, int Kpad, int mbase) {
  __shared__ float eL[4][28];
  econ_dev(eL, pts, feat, pidx, pcnt, Shi, Slo, N, Cin, K, Kpad, mbase, blockIdx.x);
}

// ---------------- FPS device code (priority wave; named scalars + pin) ----------------
template <int CTRL>
__device__ __forceinline__ float dppmaxf(float v) {
  int o = __builtin_amdgcn_update_dpp(0, __float_as_int(v), CTRL, 0xF, 0xF, true);
  return fmaxf(v, __int_as_float(o));
}
__device__ __forceinline__ float wavemaxf(float v) {
  v = dppmaxf<0xB1>(v);
  v = dppmaxf<0x4E>(v);
  v = dppmaxf<0x141>(v);
  v = dppmaxf<0x140>(v);
  v = dppmaxf<0x142>(v);
  v = dppmaxf<0x143>(v);
  return __uint_as_float((unsigned)__builtin_amdgcn_readlane(__float_as_int(v), 63));
}

#define FPS_LOAD(i) \
  float qx##i = src[3 * i + 0], qy##i = src[3 * i + 1], qz##i = src[3 * i + 2];
#define FPS_PIN(i) \
  asm volatile("" : "+v"(qx##i), "+v"(qy##i), "+v"(qz##i));
#define FPS_D0A(i) \
  { float ax = __fsub_rn(qx##i, x0), ay = __fsub_rn(qy##i, y0), az = __fsub_rn(qz##i, z0); \
    d##i = __fadd_rn(__fadd_rn(__fmul_rn(ax, ax), __fmul_rn(ay, ay)), __fmul_rn(az, az)); }
#define FPS_UPD(i) \
  { float ax = __fsub_rn(qx##i, cx), ay = __fsub_rn(qy##i, cy), az = __fsub_rn(qz##i, cz); \
    float nd = __fadd_rn(__fadd_rn(__fmul_rn(ax, ax), __fmul_rn(ay, ay)), __fmul_rn(az, az)); \
    d##i = fminf(d##i, nd); }
#define FPS_SEL(i) \
  { bool e = (d##i == lbest); sx = e ? qx##i : sx; sy = e ? qy##i : sy; sz = e ? qz##i : sz; }

// fps over N=1024 (16 pts/lane); runs at wave priority 1 (serial critical path:
// co-resident econ waves on the same SIMD otherwise steal ~50% of issue slots).
__device__ __noinline__ void fps1024_dev(const float* __restrict__ P,
                                         float* __restrict__ centers, int m, int b, int t) {
  const float* src = P + t * 48;
  FPS_LOAD(0) FPS_LOAD(1) FPS_LOAD(2) FPS_LOAD(3)
  FPS_LOAD(4) FPS_LOAD(5) FPS_LOAD(6) FPS_LOAD(7)
  FPS_LOAD(8) FPS_LOAD(9) FPS_LOAD(10) FPS_LOAD(11)
  FPS_LOAD(12) FPS_LOAD(13) FPS_LOAD(14) FPS_LOAD(15)
  FPS_PIN(0) FPS_PIN(1) FPS_PIN(2) FPS_PIN(3)
  FPS_PIN(4) FPS_PIN(5) FPS_PIN(6) FPS_PIN(7)
  FPS_PIN(8) FPS_PIN(9) FPS_PIN(10) FPS_PIN(11)
  FPS_PIN(12) FPS_PIN(13) FPS_PIN(14) FPS_PIN(15)
  float x0 = P[0], y0 = P[1], z0 = P[2];
  float d0, d1, d2, d3, d4, d5, d6, d7, d8, d9, d10, d11, d12, d13, d14, d15;
  FPS_D0A(0) FPS_D0A(1) FPS_D0A(2) FPS_D0A(3)
  FPS_D0A(4) FPS_D0A(5) FPS_D0A(6) FPS_D0A(7)
  FPS_D0A(8) FPS_D0A(9) FPS_D0A(10) FPS_D0A(11)
  FPS_D0A(12) FPS_D0A(13) FPS_D0A(14) FPS_D0A(15)
  if (t == 0) {
    centers[(size_t)b * m * 3 + 0] = x0;
    centers[(size_t)b * m * 3 + 1] = y0;
    centers[(size_t)b * m * 3 + 2] = z0;
  }
  __builtin_amdgcn_s_setprio(1);
  for (int it = 1; it < m; ++it) {
    float lbest;
    {
      float a0 = fmaxf(d0, d1), a1 = fmaxf(d2, d3), a2 = fmaxf(d4, d5), a3 = fmaxf(d6, d7);
      float a4 = fmaxf(d8, d9), a5 = fmaxf(d10, d11), a6 = fmaxf(d12, d13), a7 = fmaxf(d14, d15);
      float b0 = fmaxf(a0, a1), b1 = fmaxf(a2, a3), b2 = fmaxf(a4, a5), b3 = fmaxf(a6, a7);
      lbest = fmaxf(fmaxf(b0, b1), fmaxf(b2, b3));
    }
    float sx = qx15, sy = qy15, sz = qz15;
    FPS_SEL(14) FPS_SEL(13) FPS_SEL(12) FPS_SEL(11)
    FPS_SEL(10) FPS_SEL(9) FPS_SEL(8) FPS_SEL(7)
    FPS_SEL(6) FPS_SEL(5) FPS_SEL(4) FPS_SEL(3)
    FPS_SEL(2) FPS_SEL(1) FPS_SEL(0)
    float wmax = wavemaxf(lbest);
    unsigned long long mask = __ballot(lbest == wmax);
    int fl = __ffsll((long long)mask) - 1;
    float cx = __uint_as_float((unsigned)__builtin_amdgcn_readlane(__float_as_int(sx), fl));
    float cy = __uint_as_float((unsigned)__builtin_amdgcn_readlane(__float_as_int(sy), fl));
    float cz = __uint_as_float((unsigned)__builtin_amdgcn_readlane(__float_as_int(sz), fl));
    if (t == 0) {
      centers[((size_t)b * m + it) * 3 + 0] = cx;
      centers[((size_t)b * m + it) * 3 + 1] = cy;
      centers[((size_t)b * m + it) * 3 + 2] = cz;
    }
    FPS_UPD(0) FPS_UPD(1) FPS_UPD(2) FPS_UPD(3)
    FPS_UPD(4) FPS_UPD(5) FPS_UPD(6) FPS_UPD(7)
    FPS_UPD(8) FPS_UPD(9) FPS_UPD(10) FPS_UPD(11)
    FPS_UPD(12) FPS_UPD(13) FPS_UPD(14) FPS_UPD(15)
  }
  __builtin_amdgcn_s_setprio(0);
}

// fps over N=256 (4 pts/lane)
__device__ __noinline__ void fps256_dev(const float* __restrict__ P,
                                        float* __restrict__ centers, int m, int b, int t) {
  const float* src = P + t * 12;
  FPS_LOAD(0) FPS_LOAD(1) FPS_LOAD(2) FPS_LOAD(3)
  FPS_PIN(0) FPS_PIN(1) FPS_PIN(2) FPS_PIN(3)
  float x0 = P[0], y0 = P[1], z0 = P[2];
  float d0, d1, d2, d3;
  FPS_D0A(0) FPS_D0A(1) FPS_D0A(2) FPS_D0A(3)
  if (t == 0) {
    centers[(size_t)b * m * 3 + 0] = x0;
    centers[(size_t)b * m * 3 + 1] = y0;
    centers[(size_t)b * m * 3 + 2] = z0;
  }
  __builtin_amdgcn_s_setprio(1);
  for (int it = 1; it < m; ++it) {
    float lbest = fmaxf(fmaxf(d0, d1), fmaxf(d2, d3));
    float sx = qx3, sy = qy3, sz = qz3;
    FPS_SEL(2) FPS_SEL(1) FPS_SEL(0)
    float wmax = wavemaxf(lbest);
    unsigned long long mask = __ballot(lbest == wmax);
    int fl = __ffsll((long long)mask) - 1;
    float cx = __uint_as_float((unsigned)__builtin_amdgcn_readlane(__float_as_int(sx), fl));
    float cy = __uint_as_float((unsigned)__builtin_amdgcn_readlane(__float_as_int(sy), fl));
    float cz = __uint_as_float((unsigned)__builtin_amdgcn_readlane(__float_as_int(sz), fl));
    if (t == 0) {
      centers[((size_t)b * m + it) * 3 + 0] = cx;
      centers[((size_t)b * m + it) * 3 + 1] = cy;
      centers[((size_t)b * m + it) * 3 + 2] = cz;
    }
    FPS_UPD(0) FPS_UPD(1) FPS_UPD(2) FPS_UPD(3)
  }
  __builtin_amdgcn_s_setprio(0);
}

// ---------------- fused econtract + FPS (last B blocks run FPS) ----------------
__global__ __launch_bounds__(64, 1) void k_econtract_fps(
    const float* __restrict__ pts, const float* __restrict__ feat,
    const int* __restrict__ pidx, const int* __restrict__ pcnt,
    u16* __restrict__ Shi, u16* __restrict__ Slo,
    int N, int Cin, int K, int Kpad, int mbase,
    int fpsMode, const float* __restrict__ fpsPts, float* __restrict__ fpsCenters, int fpsM) {
  __shared__ float eL[4][28];
  const int nEcon = gridDim.x - B;
  if ((int)blockIdx.x >= nEcon) {
    const int b = blockIdx.x - nEcon;
    const int t = threadIdx.x;
    if (fpsMode == 1) fps1024_dev(fpsPts + (size_t)b * 1024 * 3, fpsCenters, fpsM, b, t);
    else fps256_dev(fpsPts + (size_t)b * 256 * 3, fpsCenters, fpsM, b, t);
    return;
  }
  econ_dev(eL, pts, feat, pidx, pcnt, Shi, Slo, N, Cin, K, Kpad, mbase, blockIdx.x);
}

// ---------------- stage 2: MFMA GEMM (clean) ----------------
__global__ __launch_bounds__(512) void k_gemm_mfma(const u16* __restrict__ Shi,
                                                   const u16* __restrict__ Slo,
                                                   const float* __restrict__ W,
                                                   const float* __restrict__ bias,
                                                   float* __restrict__ out,
                                                   float* __restrict__ P,
                                                   int K, int Kpad, int Cout, float scale,
                                                   int mcur) {
  __shared__ u16 As[2][2][32][40];
  __shared__ u16 Bs[2][2][64][40];
  __shared__ float xch[4][64][8];
  const int t = threadIdx.x;
  const int h = t >> 8;
  const int tl = t & 255;
  const int nb = blockIdx.x * 64;
  const int m0 = blockIdx.y * 32;
  const int l = t & 63, w = t >> 6;
  const int ks = w >> 2, wq = w & 3;
  const int wm = (wq >> 1) * 16, wn = (wq & 1) * 32;
  const int la = l & 15, lg = l >> 4;
  const int ntiles = Kpad >> 6;
  const int KZ = gridDim.z, z = blockIdx.z;
  const int q = ntiles / KZ, r = ntiles % KZ;
  const int t0 = z * q + (z < r ? z : r);
  const int cnt = q + (z < r ? 1 : 0);
  const int ar = tl >> 3, ak = (tl & 7) * 4;
  const size_t aOff = (size_t)(m0 + ar) * Kpad + h * 32 + ak;
  const int aw = swk2(ar, ak);
  const int kp = (tl >> 4) * 2, n4 = (tl & 15) * 4;
  f32x4 acc0 = {0.f, 0.f, 0.f, 0.f}, acc1 = {0.f, 0.f, 0.f, 0.f};

  for (int kt = 0; kt < cnt; ++kt) {
    const int k0 = (t0 + kt) * 64;
    *(ushort4*)&As[h][0][ar][aw] = *(const ushort4*)(Shi + aOff + k0);
    *(ushort4*)&As[h][1][ar][aw] = *(const ushort4*)(Slo + aOff + k0);
    {
      int gk0 = k0 + h * 32 + kp;
      float4 b0 = make_float4(0.f, 0.f, 0.f, 0.f), b1 = b0;
      if (gk0 < K) b0 = *(const float4*)(W + (size_t)gk0 * Cout + nb + n4);
      if (gk0 + 1 < K) b1 = *(const float4*)(W + (size_t)(gk0 + 1) * Cout + nb + n4);
      float v0[4] = {b0.x, b0.y, b0.z, b0.w};
      float v1[4] = {b1.x, b1.y, b1.z, b1.w};
#pragma unroll
      for (int e = 0; e < 4; ++e) {
        int n = n4 + e;
        int kw = swk2(n, kp);
        u16 h0 = f2bf(v0[e]);
        u16 l0 = f2bf(v0[e] - bf2f(h0));
        u16 h1 = f2bf(v1[e]);
        u16 l1 = f2bf(v1[e] - bf2f(h1));
        *(unsigned*)&Bs[h][0][n][kw] = (unsigned)h0 | ((unsigned)h1 << 16);
        *(unsigned*)&Bs[h][1][n][kw] = (unsigned)l0 | ((unsigned)l1 << 16);
      }
    }
    __syncthreads();
    bf16x8 ah = *(const bf16x8*)&As[ks][0][wm + la][swk2(wm + la, lg * 8)];
    bf16x8 al = *(const bf16x8*)&As[ks][1][wm + la][swk2(wm + la, lg * 8)];
    bf16x8 bh0 = *(const bf16x8*)&Bs[ks][0][wn + la][swk2(wn + la, lg * 8)];
    bf16x8 bl0 = *(const bf16x8*)&Bs[ks][1][wn + la][swk2(wn + la, lg * 8)];
    bf16x8 bh1 = *(const bf16x8*)&Bs[ks][0][wn + 16 + la][swk2(wn + 16 + la, lg * 8)];
    bf16x8 bl1 = *(const bf16x8*)&Bs[ks][1][wn + 16 + la][swk2(wn + 16 + la, lg * 8)];
    acc0 = __builtin_amdgcn_mfma_f32_16x16x32_bf16(ah, bh0, acc0, 0, 0, 0);
    acc1 = __builtin_amdgcn_mfma_f32_16x16x32_bf16(ah, bh1, acc1, 0, 0, 0);
    acc0 = __builtin_amdgcn_mfma_f32_16x16x32_bf16(al, bh0, acc0, 0, 0, 0);
    acc1 = __builtin_amdgcn_mfma_f32_16x16x32_bf16(al, bh1, acc1, 0, 0, 0);
    acc0 = __builtin_amdgcn_mfma_f32_16x16x32_bf16(ah, bl0, acc0, 0, 0, 0);
    acc1 = __builtin_amdgcn_mfma_f32_16x16x32_bf16(ah, bl1, acc1, 0, 0, 0);
    __syncthreads();
  }
  if (w >= 4) {
#pragma unroll
    for (int r2 = 0; r2 < 4; ++r2) { xch[wq][l][r2] = acc0[r2]; xch[wq][l][r2 + 4] = acc1[r2]; }
  }
  __syncthreads();
  if (w < 4) {
#pragma unroll
    for (int r2 = 0; r2 < 4; ++r2) { acc0[r2] += xch[wq][l][r2]; acc1[r2] += xch[wq][l][r2 + 4]; }
    if (gridDim.z == 1) {
#pragma unroll
      for (int r2 = 0; r2 < 4; ++r2) {
        int gm = m0 + wm + lg * 4 + r2;
        int gn0 = nb + wn + la;
        out[(size_t)gm * Cout + gn0] = fmaxf(fmaf(acc0[r2], scale, bias[gn0]), 0.f);
        int gn1 = gn0 + 16;
        out[(size_t)gm * Cout + gn1] = fmaxf(fmaf(acc1[r2], scale, bias[gn1]), 0.f);
      }
    } else {
      float* Pz = P + (size_t)z * mcur * Cout;
#pragma unroll
      for (int r2 = 0; r2 < 4; ++r2) {
        int gm = m0 + wm + lg * 4 + r2;
        int gn0 = nb + wn + la;
        Pz[(size_t)gm * Cout + gn0] = acc0[r2];
        Pz[(size_t)gm * Cout + gn0 + 16] = acc1[r2];
      }
    }
  }
}

// ---------------- split-K reduce ----------------
__global__ __launch_bounds__(256) void k_reduce(const float* __restrict__ P,
                                                const float* __restrict__ bias,
                                                float* __restrict__ out,
                                                int n4, int Cout, int KZ, float scale,
                                                int stride) {
  int i = blockIdx.x * 256 + threadIdx.x;
  if (i >= n4) return;
  float4 s = *(const float4*)(P + (size_t)i * 4);
  for (int z = 1; z < KZ; ++z) {
    float4 v = *(const float4*)(P + (size_t)z * stride + (size_t)i * 4);
    s.x += v.x; s.y += v.y; s.z += v.z; s.w += v.w;
  }
  int c = (i * 4) % Cout;
  float4 bb = *(const float4*)(bias + c);
  float4 o;
  o.x = fmaxf(fmaf(s.x, scale, bb.x), 0.f);
  o.y = fmaxf(fmaf(s.y, scale, bb.y), 0.f);
  o.z = fmaxf(fmaf(s.z, scale, bb.z), 0.f);
  o.w = fmaxf(fmaf(s.w, scale, bb.w), 0.f);
  *(float4*)(out + (size_t)i * 4) = o;
}

// level-2 (m=1): center = first point; init assign=0
__global__ __launch_bounds__(64) void k_center0(const float* __restrict__ pts,
                                                float* __restrict__ centers,
                                                int* __restrict__ assign) {
  const int b = blockIdx.x, t = threadIdx.x;
  if (t < 3) centers[b * 3 + t] = pts[(size_t)b * 64 * 3 + t];
  assign[b * 64 + t] = 0;
}

// ---------------- assignment ----------------
__global__ __launch_bounds__(256) void k_assign(const float* __restrict__ pts,
                                                const float* __restrict__ centers,
                                                int* __restrict__ assign, int N, int m) {
  __shared__ float cs[256 * 3];
  const int t = threadIdx.x;
  const int idx = blockIdx.x * 256 + t;
  const int b = (blockIdx.x * 256) / N;
  for (int i = t; i < m * 3; i += 256) cs[i] = centers[(size_t)b * m * 3 + i];
  __syncthreads();
  float px = pts[(size_t)idx * 3 + 0], py = pts[(size_t)idx * 3 + 1], pz = pts[(size_t)idx * 3 + 2];
  float best = 3.4e38f; int bk = 0;
  for (int k = 0; k < m; ++k) {
    float dx = __fsub_rn(px, cs[k * 3 + 0]);
    float dy = __fsub_rn(py, cs[k * 3 + 1]);
    float dz = __fsub_rn(pz, cs[k * 3 + 2]);
    float dd = __fadd_rn(__fadd_rn(__fmul_rn(dx, dx), __fmul_rn(dy, dy)), __fmul_rn(dz, dz));
    if (dd < best) { best = dd; bk = k; }
  }
  assign[idx] = bk;
}

// segment max via int atomicMax
__global__ __launch_bounds__(256) void k_segmax(const float* __restrict__ feat,
                                                const int* __restrict__ assign,
                                                float* __restrict__ pooled,
                                                int N, int m, int C) {
  int idx = blockIdx.x * blockDim.x + threadIdx.x;
  if (idx >= B * N * C) return;
  int b = idx / (N * C);
  int r = idx - b * N * C;
  int i = r / C;
  int c = r - i * C;
  int a = assign[b * N + i];
  atomicMax((int*)&pooled[((size_t)b * m + a) * C + c], __float_as_int(feat[idx]));
}

// ---------------- FC ----------------
template <int K, int COUT, bool BNR>
__global__ __launch_bounds__(256) void k_fc(const float* __restrict__ x,
                                            const float* __restrict__ w,
                                            const float* __restrict__ g,
                                            const float* __restrict__ be,
                                            float* __restrict__ out) {
  __shared__ float ys[8][33];
  int t = threadIdx.x;
  int n = t >> 5, cl = t & 31;
  int c = blockIdx.x * 32 + cl;
  float acc = 0.f;
  if (c < COUT) {
    const float* xr = x + n * K;
    float a0 = 0.f, a1 = 0.f, a2 = 0.f, a3 = 0.f;
    for (int k = 0; k < K; k += 4) {
      a0 = fmaf(xr[k + 0], w[(size_t)(k + 0) * COUT + c], a0);
      a1 = fmaf(xr[k + 1], w[(size_t)(k + 1) * COUT + c], a1);
      a2 = fmaf(xr[k + 2], w[(size_t)(k + 2) * COUT + c], a2);
      a3 = fmaf(xr[k + 3], w[(size_t)(k + 3) * COUT + c], a3);
    }
    acc = (a0 + a1) + (a2 + a3);
  }
  ys[n][cl] = acc;
  __syncthreads();
  if (c >= COUT) return;
  if (BNR) {
    float mu = 0.f;
#pragma unroll
    for (int q = 0; q < 8; ++q) mu += ys[q][cl];
    mu *= 0.125f;
    float var = 0.f;
#pragma unroll
    for (int q = 0; q < 8; ++q) { float dv = ys[q][cl] - mu; var = fmaf(dv, dv, var); }
    var *= 0.125f;
    float rs = 1.f / sqrtf(var + 1e-5f);
    float v = g[c] * (acc - mu) * rs + be[c];
    out[n * COUT + c] = fmaxf(v, 0.f);
  } else {
    out[n * COUT + c] = acc + be[c];
  }
}

// ---------------- launcher ----------------
extern "C" void kernel_launch(void* const* d_in, const int* in_sizes, int n_in,
                              void* d_out, int out_size, void* d_ws, size_t ws_size,
                              hipStream_t stream) {
  (void)in_sizes; (void)n_in; (void)out_size;
  const float* pc = (const float*)d_in[0];
  const float* Wc[6]; const float* bc[6];
  for (int l = 0; l < 6; ++l) { Wc[l] = (const float*)d_in[1 + 2 * l]; bc[l] = (const float*)d_in[2 + 2 * l]; }
  const float* w1 = (const float*)d_in[13];
  const float* g1 = (const float*)d_in[14];
  const float* be1 = (const float*)d_in[15];
  const float* w2 = (const float*)d_in[16];
  const float* g2 = (const float*)d_in[17];
  const float* be2 = (const float*)d_in[18];
  const float* w3 = (const float*)d_in[19];
  const float* b3 = (const float*)d_in[20];

  float* ws = (float*)d_ws;
  size_t o = 0;
  auto A = [&](size_t n) { size_t r = o; o += (n + 63) & ~(size_t)63; return r; };
  const size_t PTS0 = A((size_t)B * 1024 * 3);
  const size_t PTS1 = A((size_t)B * 256 * 3);
  const size_t PTS2 = A((size_t)B * 64 * 3);
  const size_t PTS3 = A((size_t)B * 3);
  const size_t F0  = A((size_t)B * 1024 * 4);
  const size_t FB1 = A((size_t)B * 1024 * 64);
  const size_t FB2 = A((size_t)B * 1024 * 64);
  const size_t FB3 = A((size_t)B * 256 * 64);
  const size_t FB4 = A((size_t)B * 256 * 128);
  const size_t FB5 = A((size_t)B * 256 * 128);
  const size_t FB6 = A((size_t)B * 64 * 128);
  const size_t FB7 = A((size_t)B * 64 * 256);
  const size_t FB8 = A((size_t)B * 64 * 1024);
  const size_t FB9 = A((size_t)B * 1024);
  const size_t ASSIGN = A((size_t)B * 1024);
  const size_t Y1 = A((size_t)8 * 512);
  const size_t Y2 = A((size_t)8 * 256);
  const size_t PIDX = A((size_t)B * 1024 * CAP);
  const size_t PCNT = A((size_t)B * 1024);
  const size_t dynB = o * sizeof(float);

  int* pidx = (int*)(ws + PIDX);
  int* pcnt = (int*)(ws + PCNT);

  k_prep<<<dim3((B * N0 + 255) / 256), dim3(256), 0, stream>>>(
      pc, ws + PTS0, ws + F0,
      (uint4*)(ws + FB3), B * 256 * 64 / 4,
      (uint4*)(ws + FB6), B * 64 * 128 / 4,
      (uint4*)(ws + FB9), B * 1024 / 4);

  // fpsMode: 0 none; 1 fuse fps1024 whole; 2 fuse fps256 whole (in first econ launch)
  auto conv = [&](size_t ptsOff, size_t finOff, size_t foutOff, int Npts, int Cin, int Cout,
                  const float* W, const float* bias,
                  int fpsMode, size_t fpsPtsOff, size_t fpsCtrOff, int fpsM) {
    const int M = B * Npts;
    const int K = 27 * Cin;
    const int Kpad = (K + 63) & ~63;
    const size_t availB = (ws_size > dynB) ? ws_size - dynB : 0;
    size_t pResB = availB / 4;
    if (pResB > (size_t)13 << 20) pResB = (size_t)13 << 20;
    const size_t sByte = availB - pResB;
    long mc = (long)(sByte / ((size_t)Kpad * 4)) & ~31L;
    int Mc = (int)((mc < (long)M) ? mc : (long)M);
    if (Mc < 32) Mc = 32;
    u16* Shi = (u16*)((char*)d_ws + dynB);
    u16* Slo = Shi + (size_t)Mc * Kpad;
    float* P = (float*)(Shi + (size_t)2 * Mc * Kpad);
    const int mch = (M + Mc - 1) / Mc;
    const float scale = 1.f / (float)Npts;
    const int blk = (Cin <= 64) ? 64 : Cin;
    const int ntiles = Kpad >> 6;
    for (int mcb = 0; mcb < mch; ++mcb) {
      const int mb0 = mcb * Mc;
      const int mcur = ((M - mb0) < Mc) ? (M - mb0) : Mc;
      if (mcb == 0 && fpsMode && blk == 64) {
        k_econtract_fps<<<dim3(mcur + B), dim3(64), 0, stream>>>(
            ws + ptsOff, ws + finOff, pidx, pcnt, Shi, Slo, Npts, Cin, K, Kpad, mb0,
            fpsMode, ws + fpsPtsOff, ws + fpsCtrOff, fpsM);
      } else {
        k_econtract<<<dim3(mcur), dim3(blk), 0, stream>>>(ws + ptsOff, ws + finOff, pidx, pcnt,
                                                          Shi, Slo, Npts, Cin, K, Kpad, mb0);
      }
      const int gx = Cout / 64, gy = mcur / 32;
      int kz = 1024 / (gx * gy);
      if (kz < 1) kz = 1;
      if (kz > ntiles) kz = ntiles;
      if (kz > 16) kz = 16;
      long pcap = (long)(pResB / ((size_t)mcur * Cout * 4));
      if ((long)kz > pcap) kz = (pcap < 1) ? 1 : (int)pcap;
      float* outp = ws + foutOff + (size_t)mb0 * Cout;
      k_gemm_mfma<<<dim3(gx, gy, kz), dim3(512), 0, stream>>>(
          Shi, Slo, W, bias, outp, P, K, Kpad, Cout, scale, mcur);
      if (kz > 1) {
        int n4 = mcur * Cout / 4;
        k_reduce<<<dim3((n4 + 255) / 256), dim3(256), 0, stream>>>(
            P, bias, outp, n4, Cout, kz, scale, mcur * Cout);
      }
    }
  };

  // ---- level 0 ----
  k_pairs<<<dim3(B * 1024 / 4), dim3(256), 0, stream>>>(ws + PTS0, pidx, pcnt, 1024);
  conv(PTS0, F0, FB1, 1024, 4, 64, Wc[0], bc[0], 0, 0, 0, 0);
  // conv2 hosts fps1024 (PTS0 -> PTS1, m=256) in its first econ launch (priority wave)
  conv(PTS0, FB1, FB2, 1024, 64, 64, Wc[1], bc[1], 1, PTS0, PTS1, 256);
  k_assign<<<dim3(B * 1024 / 256), dim3(256), 0, stream>>>(ws + PTS0, ws + PTS1, (int*)(ws + ASSIGN), 1024, 256);
  k_segmax<<<dim3((B * 1024 * 64 + 255) / 256), dim3(256), 0, stream>>>(ws + FB2, (int*)(ws + ASSIGN), ws + FB3, 1024, 256, 64);
  // ---- level 1 ----
  k_pairs<<<dim3(B * 256 / 4), dim3(256), 0, stream>>>(ws + PTS1, pidx, pcnt, 256);
  // conv3 hosts fps256 (PTS1 -> PTS2, m=64)
  conv(PTS1, FB3, FB4, 256, 64, 128, Wc[2], bc[2], 2, PTS1, PTS2, 64);
  conv(PTS1, FB4, FB5, 256, 128, 128, Wc[3], bc[3], 0, 0, 0, 0);
  k_assign<<<dim3(B * 256 / 256), dim3(256), 0, stream>>>(ws + PTS1, ws + PTS2, (int*)(ws + ASSIGN), 256, 64);
  k_segmax<<<dim3((B * 256 * 128 + 255) / 256), dim3(256), 0, stream>>>(ws + FB5, (int*)(ws + ASSIGN), ws + FB6, 256, 64, 128);
  // ---- level 2 ----
  k_pairs<<<dim3(B * 64 / 4), dim3(256), 0, stream>>>(ws + PTS2, pidx, pcnt, 64);
  conv(PTS2, FB6, FB7, 64, 128, 256, Wc[4], bc[4], 0, 0, 0, 0);
  conv(PTS2, FB7, FB8, 64, 256, 1024, Wc[5], bc[5], 0, 0, 0, 0);
  k_center0<<<dim3(B), dim3(64), 0, stream>>>(ws + PTS2, ws + PTS3, (int*)(ws + ASSIGN));
  k_segmax<<<dim3((B * 64 * 1024 + 255) / 256), dim3(256), 0, stream>>>(ws + FB8, (int*)(ws + ASSIGN), ws + FB9, 64, 1, 1024);
  // ---- FC head ----
  k_fc<1024, 512, true><<<dim3(512 / 32), dim3(256), 0, stream>>>(ws + FB9, w1, g1, be1, ws + Y1);
  k_fc<512, 256, true><<<dim3(256 / 32), dim3(256), 0, stream>>>(ws + Y1, w2, g2, be2, ws + Y2);
  k_fc<256, 40, false><<<dim3(2), dim3(256), 0, stream>>>(ws + Y2, w3, nullptr, b3, (float*)d_out);
}

// Round 21
// 418.582 us; speedup vs baseline: 1.3486x; 1.0218x over previous
//
#include <hip/hip_runtime.h>
#include <cstdint>
#include <cstddef>
#include <cmath>

constexpr int B = 8;
constexpr int N0 = 1024;
constexpr int CAP = 64;
using u16 = unsigned short;

typedef __bf16 bf16x8 __attribute__((ext_vector_type(8)));
typedef float f32x4 __attribute__((ext_vector_type(4)));

__device__ inline u16 f2bf(float x) {
  unsigned u = __float_as_uint(x);
  return (u16)((u + 0x7fffu + ((u >> 16) & 1u)) >> 16);
}
__device__ inline float bf2f(u16 h) { return __uint_as_float(((unsigned)h) << 16); }
__device__ inline int swk2(int row, int k) {
  int s = (((row >> 2) ^ (row >> 4)) & 3);
  return ((((k >> 3) ^ s) << 3) | (k & 7));
}

// ---------------- prep: transpose + feat0 + pooled-buffer init ----------------
__global__ __launch_bounds__(256) void k_prep(const float* __restrict__ pc,
                                              float* __restrict__ pts,
                                              float* __restrict__ feat0,
                                              uint4* __restrict__ p3, int n3,
                                              uint4* __restrict__ p6, int n6,
                                              uint4* __restrict__ p9, int n9) {
  int idx = blockIdx.x * blockDim.x + threadIdx.x;
  if (idx < B * N0) {
    int b = idx / N0, i = idx - b * N0;
    float x = pc[(b * 3 + 0) * N0 + i];
    float y = pc[(b * 3 + 1) * N0 + i];
    float z = pc[(b * 3 + 2) * N0 + i];
    pts[idx * 3 + 0] = x; pts[idx * 3 + 1] = y; pts[idx * 3 + 2] = z;
    feat0[idx * 4 + 0] = x; feat0[idx * 4 + 1] = y; feat0[idx * 4 + 2] = z; feat0[idx * 4 + 3] = 1.0f;
  }
  uint4 v = make_uint4(0xFFFFFFFFu, 0xFFFFFFFFu, 0xFFFFFFFFu, 0xFFFFFFFFu);
  for (int i = idx; i < n3; i += B * N0) p3[i] = v;
  for (int i = idx; i < n6; i += B * N0) p6[i] = v;
  for (int i = idx; i < n9; i += B * N0) p9[i] = v;
}

// ---------------- pair lists ----------------
__global__ __launch_bounds__(256) void k_pairs(const float* __restrict__ pts,
                                               int* __restrict__ pidx, int* __restrict__ pcnt,
                                               int N) {
  const int r = blockIdx.x * 4 + (threadIdx.x >> 6);
  const int lane = threadIdx.x & 63;
  const int b = r / N;
  const float px = pts[(size_t)r * 3 + 0];
  const float py = pts[(size_t)r * 3 + 1];
  const float pz = pts[(size_t)r * 3 + 2];
  int* row = pidx + (size_t)r * CAP;
  int base = 0;
  for (int j0 = 0; j0 < N; j0 += 64) {
    int j = j0 + lane;
    float dx = px - pts[((size_t)b * N + j) * 3 + 0];
    float dy = py - pts[((size_t)b * N + j) * 3 + 1];
    float dz = pz - pts[((size_t)b * N + j) * 3 + 2];
    float d2 = dx * dx + dy * dy + dz * dz;
    bool keep = d2 <= 0.1228f;
    unsigned long long mk = __ballot(keep);
    int pos = __popcll(mk & ((1ull << lane) - 1ull));
    if (keep) { int s = base + pos; if (s < CAP) row[s] = j; }
    base += __popcll(mk);
  }
  if (lane == 0) pcnt[r] = base < CAP ? base : CAP;
}

// ---------------- econtract body ----------------
__device__ __forceinline__ void econ_dev(float (*eL)[28],
                                         const float* __restrict__ pts,
                                         const float* __restrict__ feat,
                                         const int* __restrict__ pidx,
                                         const int* __restrict__ pcnt,
                                         u16* __restrict__ Shi, u16* __restrict__ Slo,
                                         int N, int Cin, int K, int Kpad, int mbase,
                                         int blockX) {
  const int g = mbase + blockX;
  const int b = g / N;
  const int t = threadIdx.x;
  const int w = t >> 6, lane = t & 63;
  const bool cact = t < Cin;
  const float px = pts[(size_t)g * 3 + 0];
  const float py = pts[(size_t)g * 3 + 1];
  const float pz = pts[(size_t)g * 3 + 2];
  float sxc = 0.f, syc = 0.f, szc = 0.f, cst = 0.f;
  if (lane < 27) {
    int a = lane / 9, bb = (lane / 3) % 3, cc = lane % 3;
    sxc = (a == 0) ? 64.f : ((a == 2) ? -64.f : 0.f);
    syc = (bb == 0) ? 64.f : ((bb == 2) ? -64.f : 0.f);
    szc = (cc == 0) ? 64.f : ((cc == 2) ? -64.f : 0.f);
    cst = -2.f * (float)((a != 1) + (bb != 1) + (cc != 1));
  }
  float acc[27];
#pragma unroll
  for (int l = 0; l < 27; ++l) acc[l] = 0.f;
  const int n = pcnt[g];
  const int* row = pidx + (size_t)g * CAP;
  for (int p = 0; p < n; ++p) {
    int j = row[p];
    size_t jb = (size_t)b * N + j;
    float dx = px - pts[jb * 3 + 0];
    float dy = py - pts[jb * 3 + 1];
    float dz = pz - pts[jb * 3 + 2];
    float d2 = dx * dx + dy * dy + dz * dz;
    if (lane < 27) {
      float ex = fmaf(-512.f, d2, fmaf(sxc, dx, fmaf(syc, dy, fmaf(szc, dz, cst))));
      eL[w][lane] = __expf(ex);
    }
    asm volatile("s_waitcnt lgkmcnt(0)" ::: "memory");
    __builtin_amdgcn_sched_barrier(0);
    float fv = cact ? feat[jb * Cin + t] : 0.f;
#pragma unroll
    for (int l = 0; l < 27; ++l) acc[l] = fmaf(eL[w][l], fv, acc[l]);
  }
  size_t rowo = (size_t)blockX * Kpad;
  if (cact) {
#pragma unroll
    for (int l = 0; l < 27; ++l) {
      float v = acc[l];
      u16 h = f2bf(v);
      u16 lo = f2bf(v - bf2f(h));
      Shi[rowo + (size_t)l * Cin + t] = h;
      Slo[rowo + (size_t)l * Cin + t] = lo;
    }
  }
  if (Kpad > K && t >= Cin && t < Cin + (Kpad - K)) {
    size_t po = rowo + K + (t - Cin);
    Shi[po] = 0; Slo[po] = 0;
  }
}

__global__ void k_econtract(const float* __restrict__ pts, const float* __restrict__ feat,
                            const int* __restrict__ pidx, const int* __restrict__ pcnt,
                            u16* __restrict__ Shi, u16* __restrict__ Slo,
                            int N, int Cin, int K, int Kpad, int mbase) {
  __shared__ float eL[4][28];
  econ_dev(eL, pts, feat, pidx, pcnt, Shi, Slo, N, Cin, K, Kpad, mbase, blockIdx.x);
}

// ---------------- FPS device code (priority wave; named scalars + pin) ----------------
template <int CTRL>
__device__ __forceinline__ float dppmaxf(float v) {
  int o = __builtin_amdgcn_update_dpp(0, __float_as_int(v), CTRL, 0xF, 0xF, true);
  return fmaxf(v, __int_as_float(o));
}
__device__ __forceinline__ float wavemaxf(float v) {
  v = dppmaxf<0xB1>(v);
  v = dppmaxf<0x4E>(v);
  v = dppmaxf<0x141>(v);
  v = dppmaxf<0x140>(v);
  v = dppmaxf<0x142>(v);
  v = dppmaxf<0x143>(v);
  return __uint_as_float((unsigned)__builtin_amdgcn_readlane(__float_as_int(v), 63));
}

#define FPS_LOAD(i) \
  float qx##i = src[3 * i + 0], qy##i = src[3 * i + 1], qz##i = src[3 * i + 2];
#define FPS_PIN(i) \
  asm volatile("" : "+v"(qx##i), "+v"(qy##i), "+v"(qz##i));
#define FPS_D0A(i) \
  { float ax = __fsub_rn(qx##i, x0), ay = __fsub_rn(qy##i, y0), az = __fsub_rn(qz##i, z0); \
    d##i = __fadd_rn(__fadd_rn(__fmul_rn(ax, ax), __fmul_rn(ay, ay)), __fmul_rn(az, az)); }
#define FPS_UPD(i) \
  { float ax = __fsub_rn(qx##i, cx), ay = __fsub_rn(qy##i, cy), az = __fsub_rn(qz##i, cz); \
    float nd = __fadd_rn(__fadd_rn(__fmul_rn(ax, ax), __fmul_rn(ay, ay)), __fmul_rn(az, az)); \
    d##i = fminf(d##i, nd); }
#define FPS_SEL(i) \
  { bool e = (d##i == lbest); sx = e ? qx##i : sx; sy = e ? qy##i : sy; sz = e ? qz##i : sz; }

// fps over N=1024 (16 pts/lane); wave priority 1 during the shared-CU phase.
__device__ __noinline__ void fps1024_dev(const float* __restrict__ P,
                                         float* __restrict__ centers, int m, int b, int t) {
  const float* src = P + t * 48;
  FPS_LOAD(0) FPS_LOAD(1) FPS_LOAD(2) FPS_LOAD(3)
  FPS_LOAD(4) FPS_LOAD(5) FPS_LOAD(6) FPS_LOAD(7)
  FPS_LOAD(8) FPS_LOAD(9) FPS_LOAD(10) FPS_LOAD(11)
  FPS_LOAD(12) FPS_LOAD(13) FPS_LOAD(14) FPS_LOAD(15)
  FPS_PIN(0) FPS_PIN(1) FPS_PIN(2) FPS_PIN(3)
  FPS_PIN(4) FPS_PIN(5) FPS_PIN(6) FPS_PIN(7)
  FPS_PIN(8) FPS_PIN(9) FPS_PIN(10) FPS_PIN(11)
  FPS_PIN(12) FPS_PIN(13) FPS_PIN(14) FPS_PIN(15)
  float x0 = P[0], y0 = P[1], z0 = P[2];
  float d0, d1, d2, d3, d4, d5, d6, d7, d8, d9, d10, d11, d12, d13, d14, d15;
  FPS_D0A(0) FPS_D0A(1) FPS_D0A(2) FPS_D0A(3)
  FPS_D0A(4) FPS_D0A(5) FPS_D0A(6) FPS_D0A(7)
  FPS_D0A(8) FPS_D0A(9) FPS_D0A(10) FPS_D0A(11)
  FPS_D0A(12) FPS_D0A(13) FPS_D0A(14) FPS_D0A(15)
  if (t == 0) {
    centers[(size_t)b * m * 3 + 0] = x0;
    centers[(size_t)b * m * 3 + 1] = y0;
    centers[(size_t)b * m * 3 + 2] = z0;
  }
  __builtin_amdgcn_s_setprio(1);
  for (int it = 1; it < m; ++it) {
    float lbest;
    {
      float a0 = fmaxf(d0, d1), a1 = fmaxf(d2, d3), a2 = fmaxf(d4, d5), a3 = fmaxf(d6, d7);
      float a4 = fmaxf(d8, d9), a5 = fmaxf(d10, d11), a6 = fmaxf(d12, d13), a7 = fmaxf(d14, d15);
      float b0 = fmaxf(a0, a1), b1 = fmaxf(a2, a3), b2 = fmaxf(a4, a5), b3 = fmaxf(a6, a7);
      lbest = fmaxf(fmaxf(b0, b1), fmaxf(b2, b3));
    }
    float sx = qx15, sy = qy15, sz = qz15;
    FPS_SEL(14) FPS_SEL(13) FPS_SEL(12) FPS_SEL(11)
    FPS_SEL(10) FPS_SEL(9) FPS_SEL(8) FPS_SEL(7)
    FPS_SEL(6) FPS_SEL(5) FPS_SEL(4) FPS_SEL(3)
    FPS_SEL(2) FPS_SEL(1) FPS_SEL(0)
    float wmax = wavemaxf(lbest);
    unsigned long long mask = __ballot(lbest == wmax);
    int fl = __ffsll((long long)mask) - 1;
    float cx = __uint_as_float((unsigned)__builtin_amdgcn_readlane(__float_as_int(sx), fl));
    float cy = __uint_as_float((unsigned)__builtin_amdgcn_readlane(__float_as_int(sy), fl));
    float cz = __uint_as_float((unsigned)__builtin_amdgcn_readlane(__float_as_int(sz), fl));
    if (t == 0) {
      centers[((size_t)b * m + it) * 3 + 0] = cx;
      centers[((size_t)b * m + it) * 3 + 1] = cy;
      centers[((size_t)b * m + it) * 3 + 2] = cz;
    }
    FPS_UPD(0) FPS_UPD(1) FPS_UPD(2) FPS_UPD(3)
    FPS_UPD(4) FPS_UPD(5) FPS_UPD(6) FPS_UPD(7)
    FPS_UPD(8) FPS_UPD(9) FPS_UPD(10) FPS_UPD(11)
    FPS_UPD(12) FPS_UPD(13) FPS_UPD(14) FPS_UPD(15)
  }
  __builtin_amdgcn_s_setprio(0);
}

// fps over N=256 (4 pts/lane)
__device__ __noinline__ void fps256_dev(const float* __restrict__ P,
                                        float* __restrict__ centers, int m, int b, int t) {
  const float* src = P + t * 12;
  FPS_LOAD(0) FPS_LOAD(1) FPS_LOAD(2) FPS_LOAD(3)
  FPS_PIN(0) FPS_PIN(1) FPS_PIN(2) FPS_PIN(3)
  float x0 = P[0], y0 = P[1], z0 = P[2];
  float d0, d1, d2, d3;
  FPS_D0A(0) FPS_D0A(1) FPS_D0A(2) FPS_D0A(3)
  if (t == 0) {
    centers[(size_t)b * m * 3 + 0] = x0;
    centers[(size_t)b * m * 3 + 1] = y0;
    centers[(size_t)b * m * 3 + 2] = z0;
  }
  __builtin_amdgcn_s_setprio(1);
  for (int it = 1; it < m; ++it) {
    float lbest = fmaxf(fmaxf(d0, d1), fmaxf(d2, d3));
    float sx = qx3, sy = qy3, sz = qz3;
    FPS_SEL(2) FPS_SEL(1) FPS_SEL(0)
    float wmax = wavemaxf(lbest);
    unsigned long long mask = __ballot(lbest == wmax);
    int fl = __ffsll((long long)mask) - 1;
    float cx = __uint_as_float((unsigned)__builtin_amdgcn_readlane(__float_as_int(sx), fl));
    float cy = __uint_as_float((unsigned)__builtin_amdgcn_readlane(__float_as_int(sy), fl));
    float cz = __uint_as_float((unsigned)__builtin_amdgcn_readlane(__float_as_int(sz), fl));
    if (t == 0) {
      centers[((size_t)b * m + it) * 3 + 0] = cx;
      centers[((size_t)b * m + it) * 3 + 1] = cy;
      centers[((size_t)b * m + it) * 3 + 2] = cz;
    }
    FPS_UPD(0) FPS_UPD(1) FPS_UPD(2) FPS_UPD(3)
  }
  __builtin_amdgcn_s_setprio(0);
}

// ---------------- fused econtract + FPS (FIRST B blocks run FPS: earliest dispatch) ----------------
__global__ __launch_bounds__(64, 1) void k_econtract_fps(
    const float* __restrict__ pts, const float* __restrict__ feat,
    const int* __restrict__ pidx, const int* __restrict__ pcnt,
    u16* __restrict__ Shi, u16* __restrict__ Slo,
    int N, int Cin, int K, int Kpad, int mbase,
    int fpsMode, const float* __restrict__ fpsPts, float* __restrict__ fpsCenters, int fpsM) {
  __shared__ float eL[4][28];
  if ((int)blockIdx.x < B) {
    const int b = blockIdx.x;
    const int t = threadIdx.x;
    if (fpsMode == 1) fps1024_dev(fpsPts + (size_t)b * 1024 * 3, fpsCenters, fpsM, b, t);
    else fps256_dev(fpsPts + (size_t)b * 256 * 3, fpsCenters, fpsM, b, t);
    return;
  }
  econ_dev(eL, pts, feat, pidx, pcnt, Shi, Slo, N, Cin, K, Kpad, mbase, blockIdx.x - B);
}

// ---------------- stage 2: MFMA GEMM (clean) ----------------
__global__ __launch_bounds__(512) void k_gemm_mfma(const u16* __restrict__ Shi,
                                                   const u16* __restrict__ Slo,
                                                   const float* __restrict__ W,
                                                   const float* __restrict__ bias,
                                                   float* __restrict__ out,
                                                   float* __restrict__ P,
                                                   int K, int Kpad, int Cout, float scale,
                                                   int mcur) {
  __shared__ u16 As[2][2][32][40];
  __shared__ u16 Bs[2][2][64][40];
  __shared__ float xch[4][64][8];
  const int t = threadIdx.x;
  const int h = t >> 8;
  const int tl = t & 255;
  const int nb = blockIdx.x * 64;
  const int m0 = blockIdx.y * 32;
  const int l = t & 63, w = t >> 6;
  const int ks = w >> 2, wq = w & 3;
  const int wm = (wq >> 1) * 16, wn = (wq & 1) * 32;
  const int la = l & 15, lg = l >> 4;
  const int ntiles = Kpad >> 6;
  const int KZ = gridDim.z, z = blockIdx.z;
  const int q = ntiles / KZ, r = ntiles % KZ;
  const int t0 = z * q + (z < r ? z : r);
  const int cnt = q + (z < r ? 1 : 0);
  const int ar = tl >> 3, ak = (tl & 7) * 4;
  const size_t aOff = (size_t)(m0 + ar) * Kpad + h * 32 + ak;
  const int aw = swk2(ar, ak);
  const int kp = (tl >> 4) * 2, n4 = (tl & 15) * 4;
  f32x4 acc0 = {0.f, 0.f, 0.f, 0.f}, acc1 = {0.f, 0.f, 0.f, 0.f};

  for (int kt = 0; kt < cnt; ++kt) {
    const int k0 = (t0 + kt) * 64;
    *(ushort4*)&As[h][0][ar][aw] = *(const ushort4*)(Shi + aOff + k0);
    *(ushort4*)&As[h][1][ar][aw] = *(const ushort4*)(Slo + aOff + k0);
    {
      int gk0 = k0 + h * 32 + kp;
      float4 b0 = make_float4(0.f, 0.f, 0.f, 0.f), b1 = b0;
      if (gk0 < K) b0 = *(const float4*)(W + (size_t)gk0 * Cout + nb + n4);
      if (gk0 + 1 < K) b1 = *(const float4*)(W + (size_t)(gk0 + 1) * Cout + nb + n4);
      float v0[4] = {b0.x, b0.y, b0.z, b0.w};
      float v1[4] = {b1.x, b1.y, b1.z, b1.w};
#pragma unroll
      for (int e = 0; e < 4; ++e) {
        int n = n4 + e;
        int kw = swk2(n, kp);
        u16 h0 = f2bf(v0[e]);
        u16 l0 = f2bf(v0[e] - bf2f(h0));
        u16 h1 = f2bf(v1[e]);
        u16 l1 = f2bf(v1[e] - bf2f(h1));
        *(unsigned*)&Bs[h][0][n][kw] = (unsigned)h0 | ((unsigned)h1 << 16);
        *(unsigned*)&Bs[h][1][n][kw] = (unsigned)l0 | ((unsigned)l1 << 16);
      }
    }
    __syncthreads();
    bf16x8 ah = *(const bf16x8*)&As[ks][0][wm + la][swk2(wm + la, lg * 8)];
    bf16x8 al = *(const bf16x8*)&As[ks][1][wm + la][swk2(wm + la, lg * 8)];
    bf16x8 bh0 = *(const bf16x8*)&Bs[ks][0][wn + la][swk2(wn + la, lg * 8)];
    bf16x8 bl0 = *(const bf16x8*)&Bs[ks][1][wn + la][swk2(wn + la, lg * 8)];
    bf16x8 bh1 = *(const bf16x8*)&Bs[ks][0][wn + 16 + la][swk2(wn + 16 + la, lg * 8)];
    bf16x8 bl1 = *(const bf16x8*)&Bs[ks][1][wn + 16 + la][swk2(wn + 16 + la, lg * 8)];
    acc0 = __builtin_amdgcn_mfma_f32_16x16x32_bf16(ah, bh0, acc0, 0, 0, 0);
    acc1 = __builtin_amdgcn_mfma_f32_16x16x32_bf16(ah, bh1, acc1, 0, 0, 0);
    acc0 = __builtin_amdgcn_mfma_f32_16x16x32_bf16(al, bh0, acc0, 0, 0, 0);
    acc1 = __builtin_amdgcn_mfma_f32_16x16x32_bf16(al, bh1, acc1, 0, 0, 0);
    acc0 = __builtin_amdgcn_mfma_f32_16x16x32_bf16(ah, bl0, acc0, 0, 0, 0);
    acc1 = __builtin_amdgcn_mfma_f32_16x16x32_bf16(ah, bl1, acc1, 0, 0, 0);
    __syncthreads();
  }
  if (w >= 4) {
#pragma unroll
    for (int r2 = 0; r2 < 4; ++r2) { xch[wq][l][r2] = acc0[r2]; xch[wq][l][r2 + 4] = acc1[r2]; }
  }
  __syncthreads();
  if (w < 4) {
#pragma unroll
    for (int r2 = 0; r2 < 4; ++r2) { acc0[r2] += xch[wq][l][r2]; acc1[r2] += xch[wq][l][r2 + 4]; }
    if (gridDim.z == 1) {
#pragma unroll
      for (int r2 = 0; r2 < 4; ++r2) {
        int gm = m0 + wm + lg * 4 + r2;
        int gn0 = nb + wn + la;
        out[(size_t)gm * Cout + gn0] = fmaxf(fmaf(acc0[r2], scale, bias[gn0]), 0.f);
        int gn1 = gn0 + 16;
        out[(size_t)gm * Cout + gn1] = fmaxf(fmaf(acc1[r2], scale, bias[gn1]), 0.f);
      }
    } else {
      float* Pz = P + (size_t)z * mcur * Cout;
#pragma unroll
      for (int r2 = 0; r2 < 4; ++r2) {
        int gm = m0 + wm + lg * 4 + r2;
        int gn0 = nb + wn + la;
        Pz[(size_t)gm * Cout + gn0] = acc0[r2];
        Pz[(size_t)gm * Cout + gn0 + 16] = acc1[r2];
      }
    }
  }
}

// ---------------- split-K reduce ----------------
__global__ __launch_bounds__(256) void k_reduce(const float* __restrict__ P,
                                                const float* __restrict__ bias,
                                                float* __restrict__ out,
                                                int n4, int Cout, int KZ, float scale,
                                                int stride) {
  int i = blockIdx.x * 256 + threadIdx.x;
  if (i >= n4) return;
  float4 s = *(const float4*)(P + (size_t)i * 4);
  for (int z = 1; z < KZ; ++z) {
    float4 v = *(const float4*)(P + (size_t)z * stride + (size_t)i * 4);
    s.x += v.x; s.y += v.y; s.z += v.z; s.w += v.w;
  }
  int c = (i * 4) % Cout;
  float4 bb = *(const float4*)(bias + c);
  float4 o;
  o.x = fmaxf(fmaf(s.x, scale, bb.x), 0.f);
  o.y = fmaxf(fmaf(s.y, scale, bb.y), 0.f);
  o.z = fmaxf(fmaf(s.z, scale, bb.z), 0.f);
  o.w = fmaxf(fmaf(s.w, scale, bb.w), 0.f);
  *(float4*)(out + (size_t)i * 4) = o;
}

// level-2 (m=1): center = first point; init assign=0
__global__ __launch_bounds__(64) void k_center0(const float* __restrict__ pts,
                                                float* __restrict__ centers,
                                                int* __restrict__ assign) {
  const int b = blockIdx.x, t = threadIdx.x;
  if (t < 3) centers[b * 3 + t] = pts[(size_t)b * 64 * 3 + t];
  assign[b * 64 + t] = 0;
}

// ---------------- assignment ----------------
__global__ __launch_bounds__(256) void k_assign(const float* __restrict__ pts,
                                                const float* __restrict__ centers,
                                                int* __restrict__ assign, int N, int m) {
  __shared__ float cs[256 * 3];
  const int t = threadIdx.x;
  const int idx = blockIdx.x * 256 + t;
  const int b = (blockIdx.x * 256) / N;
  for (int i = t; i < m * 3; i += 256) cs[i] = centers[(size_t)b * m * 3 + i];
  __syncthreads();
  float px = pts[(size_t)idx * 3 + 0], py = pts[(size_t)idx * 3 + 1], pz = pts[(size_t)idx * 3 + 2];
  float best = 3.4e38f; int bk = 0;
  for (int k = 0; k < m; ++k) {
    float dx = __fsub_rn(px, cs[k * 3 + 0]);
    float dy = __fsub_rn(py, cs[k * 3 + 1]);
    float dz = __fsub_rn(pz, cs[k * 3 + 2]);
    float dd = __fadd_rn(__fadd_rn(__fmul_rn(dx, dx), __fmul_rn(dy, dy)), __fmul_rn(dz, dz));
    if (dd < best) { best = dd; bk = k; }
  }
  assign[idx] = bk;
}

// segment max via int atomicMax
__global__ __launch_bounds__(256) void k_segmax(const float* __restrict__ feat,
                                                const int* __restrict__ assign,
                                                float* __restrict__ pooled,
                                                int N, int m, int C) {
  int idx = blockIdx.x * blockDim.x + threadIdx.x;
  if (idx >= B * N * C) return;
  int b = idx / (N * C);
  int r = idx - b * N * C;
  int i = r / C;
  int c = r - i * C;
  int a = assign[b * N + i];
  atomicMax((int*)&pooled[((size_t)b * m + a) * C + c], __float_as_int(feat[idx]));
}

// ---------------- FC ----------------
template <int K, int COUT, bool BNR>
__global__ __launch_bounds__(256) void k_fc(const float* __restrict__ x,
                                            const float* __restrict__ w,
                                            const float* __restrict__ g,
                                            const float* __restrict__ be,
                                            float* __restrict__ out) {
  __shared__ float ys[8][33];
  int t = threadIdx.x;
  int n = t >> 5, cl = t & 31;
  int c = blockIdx.x * 32 + cl;
  float acc = 0.f;
  if (c < COUT) {
    const float* xr = x + n * K;
    float a0 = 0.f, a1 = 0.f, a2 = 0.f, a3 = 0.f;
    for (int k = 0; k < K; k += 4) {
      a0 = fmaf(xr[k + 0], w[(size_t)(k + 0) * COUT + c], a0);
      a1 = fmaf(xr[k + 1], w[(size_t)(k + 1) * COUT + c], a1);
      a2 = fmaf(xr[k + 2], w[(size_t)(k + 2) * COUT + c], a2);
      a3 = fmaf(xr[k + 3], w[(size_t)(k + 3) * COUT + c], a3);
    }
    acc = (a0 + a1) + (a2 + a3);
  }
  ys[n][cl] = acc;
  __syncthreads();
  if (c >= COUT) return;
  if (BNR) {
    float mu = 0.f;
#pragma unroll
    for (int q = 0; q < 8; ++q) mu += ys[q][cl];
    mu *= 0.125f;
    float var = 0.f;
#pragma unroll
    for (int q = 0; q < 8; ++q) { float dv = ys[q][cl] - mu; var = fmaf(dv, dv, var); }
    var *= 0.125f;
    float rs = 1.f / sqrtf(var + 1e-5f);
    float v = g[c] * (acc - mu) * rs + be[c];
    out[n * COUT + c] = fmaxf(v, 0.f);
  } else {
    out[n * COUT + c] = acc + be[c];
  }
}

// ---------------- launcher ----------------
extern "C" void kernel_launch(void* const* d_in, const int* in_sizes, int n_in,
                              void* d_out, int out_size, void* d_ws, size_t ws_size,
                              hipStream_t stream) {
  (void)in_sizes; (void)n_in; (void)out_size;
  const float* pc = (const float*)d_in[0];
  const float* Wc[6]; const float* bc[6];
  for (int l = 0; l < 6; ++l) { Wc[l] = (const float*)d_in[1 + 2 * l]; bc[l] = (const float*)d_in[2 + 2 * l]; }
  const float* w1 = (const float*)d_in[13];
  const float* g1 = (const float*)d_in[14];
  const float* be1 = (const float*)d_in[15];
  const float* w2 = (const float*)d_in[16];
  const float* g2 = (const float*)d_in[17];
  const float* be2 = (const float*)d_in[18];
  const float* w3 = (const float*)d_in[19];
  const float* b3 = (const float*)d_in[20];

  float* ws = (float*)d_ws;
  size_t o = 0;
  auto A = [&](size_t n) { size_t r = o; o += (n + 63) & ~(size_t)63; return r; };
  const size_t PTS0 = A((size_t)B * 1024 * 3);
  const size_t PTS1 = A((size_t)B * 256 * 3);
  const size_t PTS2 = A((size_t)B * 64 * 3);
  const size_t PTS3 = A((size_t)B * 3);
  const size_t F0  = A((size_t)B * 1024 * 4);
  const size_t FB1 = A((size_t)B * 1024 * 64);
  const size_t FB2 = A((size_t)B * 1024 * 64);
  const size_t FB3 = A((size_t)B * 256 * 64);
  const size_t FB4 = A((size_t)B * 256 * 128);
  const size_t FB5 = A((size_t)B * 256 * 128);
  const size_t FB6 = A((size_t)B * 64 * 128);
  const size_t FB7 = A((size_t)B * 64 * 256);
  const size_t FB8 = A((size_t)B * 64 * 1024);
  const size_t FB9 = A((size_t)B * 1024);
  const size_t ASSIGN = A((size_t)B * 1024);
  const size_t Y1 = A((size_t)8 * 512);
  const size_t Y2 = A((size_t)8 * 256);
  const size_t PIDX = A((size_t)B * 1024 * CAP);
  const size_t PCNT = A((size_t)B * 1024);
  const size_t dynB = o * sizeof(float);

  int* pidx = (int*)(ws + PIDX);
  int* pcnt = (int*)(ws + PCNT);

  k_prep<<<dim3((B * N0 + 255) / 256), dim3(256), 0, stream>>>(
      pc, ws + PTS0, ws + F0,
      (uint4*)(ws + FB3), B * 256 * 64 / 4,
      (uint4*)(ws + FB6), B * 64 * 128 / 4,
      (uint4*)(ws + FB9), B * 1024 / 4);

  // fpsMode: 0 none; 1 fuse fps1024 whole; 2 fuse fps256 whole (in first econ launch)
  auto conv = [&](size_t ptsOff, size_t finOff, size_t foutOff, int Npts, int Cin, int Cout,
                  const float* W, const float* bias,
                  int fpsMode, size_t fpsPtsOff, size_t fpsCtrOff, int fpsM) {
    const int M = B * Npts;
    const int K = 27 * Cin;
    const int Kpad = (K + 63) & ~63;
    const size_t availB = (ws_size > dynB) ? ws_size - dynB : 0;
    size_t pResB = availB / 4;
    if (pResB > (size_t)13 << 20) pResB = (size_t)13 << 20;
    const size_t sByte = availB - pResB;
    long mc = (long)(sByte / ((size_t)Kpad * 4)) & ~31L;
    int Mc = (int)((mc < (long)M) ? mc : (long)M);
    if (Mc < 32) Mc = 32;
    u16* Shi = (u16*)((char*)d_ws + dynB);
    u16* Slo = Shi + (size_t)Mc * Kpad;
    float* P = (float*)(Shi + (size_t)2 * Mc * Kpad);
    const int mch = (M + Mc - 1) / Mc;
    const float scale = 1.f / (float)Npts;
    const int blk = (Cin <= 64) ? 64 : Cin;
    const int ntiles = Kpad >> 6;
    for (int mcb = 0; mcb < mch; ++mcb) {
      const int mb0 = mcb * Mc;
      const int mcur = ((M - mb0) < Mc) ? (M - mb0) : Mc;
      if (mcb == 0 && fpsMode && blk == 64) {
        k_econtract_fps<<<dim3(mcur + B), dim3(64), 0, stream>>>(
            ws + ptsOff, ws + finOff, pidx, pcnt, Shi, Slo, Npts, Cin, K, Kpad, mb0,
            fpsMode, ws + fpsPtsOff, ws + fpsCtrOff, fpsM);
      } else {
        k_econtract<<<dim3(mcur), dim3(blk), 0, stream>>>(ws + ptsOff, ws + finOff, pidx, pcnt,
                                                          Shi, Slo, Npts, Cin, K, Kpad, mb0);
      }
      const int gx = Cout / 64, gy = mcur / 32;
      int kz = 1024 / (gx * gy);
      if (kz < 1) kz = 1;
      if (kz > ntiles) kz = ntiles;
      if (kz > 16) kz = 16;
      long pcap = (long)(pResB / ((size_t)mcur * Cout * 4));
      if ((long)kz > pcap) kz = (pcap < 1) ? 1 : (int)pcap;
      float* outp = ws + foutOff + (size_t)mb0 * Cout;
      k_gemm_mfma<<<dim3(gx, gy, kz), dim3(512), 0, stream>>>(
          Shi, Slo, W, bias, outp, P, K, Kpad, Cout, scale, mcur);
      if (kz > 1) {
        int n4 = mcur * Cout / 4;
        k_reduce<<<dim3((n4 + 255) / 256), dim3(256), 0, stream>>>(
            P, bias, outp, n4, Cout, kz, scale, mcur * Cout);
      }
    }
  };

  // ---- level 0 ----
  k_pairs<<<dim3(B * 1024 / 4), dim3(256), 0, stream>>>(ws + PTS0, pidx, pcnt, 1024);
  conv(PTS0, F0, FB1, 1024, 4, 64, Wc[0], bc[0], 0, 0, 0, 0);
  // conv2 hosts fps1024 (PTS0 -> PTS1, m=256); fps blocks dispatched first
  conv(PTS0, FB1, FB2, 1024, 64, 64, Wc[1], bc[1], 1, PTS0, PTS1, 256);
  k_assign<<<dim3(B * 1024 / 256), dim3(256), 0, stream>>>(ws + PTS0, ws + PTS1, (int*)(ws + ASSIGN), 1024, 256);
  k_segmax<<<dim3((B * 1024 * 64 + 255) / 256), dim3(256), 0, stream>>>(ws + FB2, (int*)(ws + ASSIGN), ws + FB3, 1024, 256, 64);
  // ---- level 1 ----
  k_pairs<<<dim3(B * 256 / 4), dim3(256), 0, stream>>>(ws + PTS1, pidx, pcnt, 256);
  // conv3 hosts fps256 (PTS1 -> PTS2, m=64)
  conv(PTS1, FB3, FB4, 256, 64, 128, Wc[2], bc[2], 2, PTS1, PTS2, 64);
  conv(PTS1, FB4, FB5, 256, 128, 128, Wc[3], bc[3], 0, 0, 0, 0);
  k_assign<<<dim3(B * 256 / 256), dim3(256), 0, stream>>>(ws + PTS1, ws + PTS2, (int*)(ws + ASSIGN), 256, 64);
  k_segmax<<<dim3((B * 256 * 128 + 255) / 256), dim3(256), 0, stream>>>(ws + FB5, (int*)(ws + ASSIGN), ws + FB6, 256, 64, 128);
  // ---- level 2 ----
  k_pairs<<<dim3(B * 64 / 4), dim3(256), 0, stream>>>(ws + PTS2, pidx, pcnt, 64);
  conv(PTS2, FB6, FB7, 64, 128, 256, Wc[4], bc[4], 0, 0, 0, 0);
  conv(PTS2, FB7, FB8, 64, 256, 1024, Wc[5], bc[5], 0, 0, 0, 0);
  k_center0<<<dim3(B), dim3(64), 0, stream>>>(ws + PTS2, ws + PTS3, (int*)(ws + ASSIGN));
  k_segmax<<<dim3((B * 64 * 1024 + 255) / 256), dim3(256), 0, stream>>>(ws + FB8, (int*)(ws + ASSIGN), ws + FB9, 64, 1, 1024);
  // ---- FC head ----
  k_fc<1024, 512, true><<<dim3(512 / 32), dim3(256), 0, stream>>>(ws + FB9, w1, g1, be1, ws + Y1);
  k_fc<512, 256, true><<<dim3(256 / 32), dim3(256), 0, stream>>>(ws + Y1, w2, g2, be2, ws + Y2);
  k_fc<256, 40, false><<<dim3(2), dim3(256), 0, stream>>>(ws + Y2, w3, nullptr, b3, (float*)d_out);
}

// Round 22
// 415.708 us; speedup vs baseline: 1.3580x; 1.0069x over previous
//
#include <hip/hip_runtime.h>
#include <cstdint>
#include <cstddef>
#include <cmath>

constexpr int B = 8;
constexpr int N0 = 1024;
constexpr int CAP = 64;
using u16 = unsigned short;

typedef __bf16 bf16x8 __attribute__((ext_vector_type(8)));
typedef float f32x4 __attribute__((ext_vector_type(4)));

__device__ inline u16 f2bf(float x) {
  unsigned u = __float_as_uint(x);
  return (u16)((u + 0x7fffu + ((u >> 16) & 1u)) >> 16);
}
__device__ inline float bf2f(u16 h) { return __uint_as_float(((unsigned)h) << 16); }
__device__ inline int swk2(int row, int k) {
  int s = (((row >> 2) ^ (row >> 4)) & 3);
  return ((((k >> 3) ^ s) << 3) | (k & 7));
}

// ---------------- FPS device code (chunked, checkpoint in fpsD; layout-agnostic) ----------------
template <int CTRL>
__device__ __forceinline__ float dppmaxf(float v) {
  int o = __builtin_amdgcn_update_dpp(0, __float_as_int(v), CTRL, 0xF, 0xF, true);
  return fmaxf(v, __int_as_float(o));
}
__device__ __forceinline__ float wavemaxf(float v) {
  v = dppmaxf<0xB1>(v);
  v = dppmaxf<0x4E>(v);
  v = dppmaxf<0x141>(v);
  v = dppmaxf<0x140>(v);
  v = dppmaxf<0x142>(v);
  v = dppmaxf<0x143>(v);
  return __uint_as_float((unsigned)__builtin_amdgcn_readlane(__float_as_int(v), 63));
}

#define FPS_LD(i) \
  float qx##i = Px[bix + i * stride], qy##i = Py[bix + i * stride], qz##i = Pz[bix + i * stride];
#define FPS_PIN(i) \
  asm volatile("" : "+v"(qx##i), "+v"(qy##i), "+v"(qz##i));
#define FPS_D0A(i) \
  { float ax = __fsub_rn(qx##i, x0), ay = __fsub_rn(qy##i, y0), az = __fsub_rn(qz##i, z0); \
    d##i = __fadd_rn(__fadd_rn(__fmul_rn(ax, ax), __fmul_rn(ay, ay)), __fmul_rn(az, az)); }
#define FPS_UPD(i) \
  { float ax = __fsub_rn(qx##i, cx), ay = __fsub_rn(qy##i, cy), az = __fsub_rn(qz##i, cz); \
    float nd = __fadd_rn(__fadd_rn(__fmul_rn(ax, ax), __fmul_rn(ay, ay)), __fmul_rn(az, az)); \
    d##i = fminf(d##i, nd); }
#define FPS_SEL(i) \
  { bool e = (d##i == lbest); sx = e ? qx##i : sx; sy = e ? qy##i : sy; sz = e ? qz##i : sz; }

// fps over N=1024 (16 pts/lane): coordinate c of point j at P{x,y,z}[j*stride].
__device__ __noinline__ void fps1024_dev(const float* __restrict__ Px,
                                         const float* __restrict__ Py,
                                         const float* __restrict__ Pz, int stride,
                                         float* __restrict__ centers, int m, int b, int t,
                                         int it0, int it1, float* __restrict__ Dst) {
  const int bix = t * 16 * stride;
  FPS_LD(0) FPS_LD(1) FPS_LD(2) FPS_LD(3)
  FPS_LD(4) FPS_LD(5) FPS_LD(6) FPS_LD(7)
  FPS_LD(8) FPS_LD(9) FPS_LD(10) FPS_LD(11)
  FPS_LD(12) FPS_LD(13) FPS_LD(14) FPS_LD(15)
  FPS_PIN(0) FPS_PIN(1) FPS_PIN(2) FPS_PIN(3)
  FPS_PIN(4) FPS_PIN(5) FPS_PIN(6) FPS_PIN(7)
  FPS_PIN(8) FPS_PIN(9) FPS_PIN(10) FPS_PIN(11)
  FPS_PIN(12) FPS_PIN(13) FPS_PIN(14) FPS_PIN(15)
  float d0, d1, d2, d3, d4, d5, d6, d7, d8, d9, d10, d11, d12, d13, d14, d15;
  if (it0 == 1) {
    float x0 = Px[0], y0 = Py[0], z0 = Pz[0];
    FPS_D0A(0) FPS_D0A(1) FPS_D0A(2) FPS_D0A(3)
    FPS_D0A(4) FPS_D0A(5) FPS_D0A(6) FPS_D0A(7)
    FPS_D0A(8) FPS_D0A(9) FPS_D0A(10) FPS_D0A(11)
    FPS_D0A(12) FPS_D0A(13) FPS_D0A(14) FPS_D0A(15)
    if (t == 0) {
      centers[(size_t)b * m * 3 + 0] = x0;
      centers[(size_t)b * m * 3 + 1] = y0;
      centers[(size_t)b * m * 3 + 2] = z0;
    }
  } else {
    const float* ds = Dst + t * 16;
    d0 = ds[0]; d1 = ds[1]; d2 = ds[2]; d3 = ds[3];
    d4 = ds[4]; d5 = ds[5]; d6 = ds[6]; d7 = ds[7];
    d8 = ds[8]; d9 = ds[9]; d10 = ds[10]; d11 = ds[11];
    d12 = ds[12]; d13 = ds[13]; d14 = ds[14]; d15 = ds[15];
  }
  __builtin_amdgcn_s_setprio(1);
  for (int it = it0; it < it1; ++it) {
    float lbest;
    {
      float a0 = fmaxf(d0, d1), a1 = fmaxf(d2, d3), a2 = fmaxf(d4, d5), a3 = fmaxf(d6, d7);
      float a4 = fmaxf(d8, d9), a5 = fmaxf(d10, d11), a6 = fmaxf(d12, d13), a7 = fmaxf(d14, d15);
      float b0 = fmaxf(a0, a1), b1 = fmaxf(a2, a3), b2 = fmaxf(a4, a5), b3 = fmaxf(a6, a7);
      lbest = fmaxf(fmaxf(b0, b1), fmaxf(b2, b3));
    }
    float sx = qx15, sy = qy15, sz = qz15;
    FPS_SEL(14) FPS_SEL(13) FPS_SEL(12) FPS_SEL(11)
    FPS_SEL(10) FPS_SEL(9) FPS_SEL(8) FPS_SEL(7)
    FPS_SEL(6) FPS_SEL(5) FPS_SEL(4) FPS_SEL(3)
    FPS_SEL(2) FPS_SEL(1) FPS_SEL(0)
    float wmax = wavemaxf(lbest);
    unsigned long long mask = __ballot(lbest == wmax);
    int fl = __ffsll((long long)mask) - 1;
    float cx = __uint_as_float((unsigned)__builtin_amdgcn_readlane(__float_as_int(sx), fl));
    float cy = __uint_as_float((unsigned)__builtin_amdgcn_readlane(__float_as_int(sy), fl));
    float cz = __uint_as_float((unsigned)__builtin_amdgcn_readlane(__float_as_int(sz), fl));
    if (t == 0) {
      centers[((size_t)b * m + it) * 3 + 0] = cx;
      centers[((size_t)b * m + it) * 3 + 1] = cy;
      centers[((size_t)b * m + it) * 3 + 2] = cz;
    }
    FPS_UPD(0) FPS_UPD(1) FPS_UPD(2) FPS_UPD(3)
    FPS_UPD(4) FPS_UPD(5) FPS_UPD(6) FPS_UPD(7)
    FPS_UPD(8) FPS_UPD(9) FPS_UPD(10) FPS_UPD(11)
    FPS_UPD(12) FPS_UPD(13) FPS_UPD(14) FPS_UPD(15)
  }
  __builtin_amdgcn_s_setprio(0);
  if (it1 < m) {
    float* ds = Dst + t * 16;
    ds[0] = d0; ds[1] = d1; ds[2] = d2; ds[3] = d3;
    ds[4] = d4; ds[5] = d5; ds[6] = d6; ds[7] = d7;
    ds[8] = d8; ds[9] = d9; ds[10] = d10; ds[11] = d11;
    ds[12] = d12; ds[13] = d13; ds[14] = d14; ds[15] = d15;
  }
}

// fps over N=256 (4 pts/lane)
__device__ __noinline__ void fps256_dev(const float* __restrict__ Px,
                                        const float* __restrict__ Py,
                                        const float* __restrict__ Pz, int stride,
                                        float* __restrict__ centers, int m, int b, int t,
                                        int it0, int it1, float* __restrict__ Dst) {
  const int bix = t * 4 * stride;
  FPS_LD(0) FPS_LD(1) FPS_LD(2) FPS_LD(3)
  FPS_PIN(0) FPS_PIN(1) FPS_PIN(2) FPS_PIN(3)
  float d0, d1, d2, d3;
  if (it0 == 1) {
    float x0 = Px[0], y0 = Py[0], z0 = Pz[0];
    FPS_D0A(0) FPS_D0A(1) FPS_D0A(2) FPS_D0A(3)
    if (t == 0) {
      centers[(size_t)b * m * 3 + 0] = x0;
      centers[(size_t)b * m * 3 + 1] = y0;
      centers[(size_t)b * m * 3 + 2] = z0;
    }
  } else {
    const float* ds = Dst + t * 4;
    d0 = ds[0]; d1 = ds[1]; d2 = ds[2]; d3 = ds[3];
  }
  __builtin_amdgcn_s_setprio(1);
  for (int it = it0; it < it1; ++it) {
    float lbest = fmaxf(fmaxf(d0, d1), fmaxf(d2, d3));
    float sx = qx3, sy = qy3, sz = qz3;
    FPS_SEL(2) FPS_SEL(1) FPS_SEL(0)
    float wmax = wavemaxf(lbest);
    unsigned long long mask = __ballot(lbest == wmax);
    int fl = __ffsll((long long)mask) - 1;
    float cx = __uint_as_float((unsigned)__builtin_amdgcn_readlane(__float_as_int(sx), fl));
    float cy = __uint_as_float((unsigned)__builtin_amdgcn_readlane(__float_as_int(sy), fl));
    float cz = __uint_as_float((unsigned)__builtin_amdgcn_readlane(__float_as_int(sz), fl));
    if (t == 0) {
      centers[((size_t)b * m + it) * 3 + 0] = cx;
      centers[((size_t)b * m + it) * 3 + 1] = cy;
      centers[((size_t)b * m + it) * 3 + 2] = cz;
    }
    FPS_UPD(0) FPS_UPD(1) FPS_UPD(2) FPS_UPD(3)
  }
  __builtin_amdgcn_s_setprio(0);
  if (it1 < m) {
    float* ds = Dst + t * 4;
    ds[0] = d0; ds[1] = d1; ds[2] = d2; ds[3] = d3;
  }
}

// helper: dispatch fps chunk from pts-layout source
__device__ __forceinline__ void fps_run(int mode, const float* __restrict__ fpsPts,
                                        float* __restrict__ centers, int m,
                                        int b, int t, int it0, int it1,
                                        float* __restrict__ fpsD) {
  if (mode == 1) {
    const float* Px = fpsPts + (size_t)b * 3072;
    fps1024_dev(Px, Px + 1, Px + 2, 3, centers, m, b, t, it0, it1, fpsD + (size_t)b * 1024);
  } else {
    const float* Px = fpsPts + (size_t)b * 768;
    fps256_dev(Px, Px + 1, Px + 2, 3, centers, m, b, t, it0, it1, fpsD + (size_t)b * 256);
  }
}

// ---------------- prep + fps1024 chunk [1,65) (reads pc directly: no race with pts writes) ----------------
__global__ __launch_bounds__(256, 1) void k_prep(const float* __restrict__ pc,
                                                 float* __restrict__ pts,
                                                 float* __restrict__ feat0,
                                                 uint4* __restrict__ p3, int n3,
                                                 uint4* __restrict__ p6, int n6,
                                                 uint4* __restrict__ p9, int n9,
                                                 float* __restrict__ fpsCenters,
                                                 float* __restrict__ fpsD) {
  const int t = threadIdx.x;
  if ((int)blockIdx.x < B) {
    if (t >= 64) return;
    const int b = blockIdx.x;
    const float* Px = pc + (size_t)b * 3 * 1024;
    fps1024_dev(Px, Px + 1024, Px + 2048, 1, fpsCenters, 256, b, t, 1, 65,
                fpsD + (size_t)b * 1024);
    return;
  }
  int idx = (blockIdx.x - B) * 256 + t;
  if (idx < B * N0) {
    int b = idx / N0, i = idx - b * N0;
    float x = pc[(b * 3 + 0) * N0 + i];
    float y = pc[(b * 3 + 1) * N0 + i];
    float z = pc[(b * 3 + 2) * N0 + i];
    pts[idx * 3 + 0] = x; pts[idx * 3 + 1] = y; pts[idx * 3 + 2] = z;
    feat0[idx * 4 + 0] = x; feat0[idx * 4 + 1] = y; feat0[idx * 4 + 2] = z; feat0[idx * 4 + 3] = 1.0f;
  }
  uint4 v = make_uint4(0xFFFFFFFFu, 0xFFFFFFFFu, 0xFFFFFFFFu, 0xFFFFFFFFu);
  for (int i = idx; i < n3; i += B * N0) p3[i] = v;
  for (int i = idx; i < n6; i += B * N0) p6[i] = v;
  for (int i = idx; i < n9; i += B * N0) p9[i] = v;
}

// ---------------- pair lists (+optional fps chunk in first B blocks) ----------------
__global__ __launch_bounds__(256, 1) void k_pairs_f(const float* __restrict__ pts,
                                                    int* __restrict__ pidx, int* __restrict__ pcnt,
                                                    int N,
                                                    int fpsMode, const float* __restrict__ fpsPts,
                                                    float* __restrict__ fpsCenters, int fpsM,
                                                    int it0, int it1, float* __restrict__ fpsD) {
  const int t = threadIdx.x;
  if (fpsMode && (int)blockIdx.x < B) {
    if (t >= 64) return;
    fps_run(fpsMode, fpsPts, fpsCenters, fpsM, blockIdx.x, t, it0, it1, fpsD);
    return;
  }
  const int boff = fpsMode ? B : 0;
  const int r = (blockIdx.x - boff) * 4 + (t >> 6);
  const int lane = t & 63;
  const int b = r / N;
  const float px = pts[(size_t)r * 3 + 0];
  const float py = pts[(size_t)r * 3 + 1];
  const float pz = pts[(size_t)r * 3 + 2];
  int* row = pidx + (size_t)r * CAP;
  int base = 0;
  for (int j0 = 0; j0 < N; j0 += 64) {
    int j = j0 + lane;
    float dx = px - pts[((size_t)b * N + j) * 3 + 0];
    float dy = py - pts[((size_t)b * N + j) * 3 + 1];
    float dz = pz - pts[((size_t)b * N + j) * 3 + 2];
    float d2 = dx * dx + dy * dy + dz * dz;
    bool keep = d2 <= 0.1228f;
    unsigned long long mk = __ballot(keep);
    int pos = __popcll(mk & ((1ull << lane) - 1ull));
    if (keep) { int s = base + pos; if (s < CAP) row[s] = j; }
    base += __popcll(mk);
  }
  if (lane == 0) pcnt[r] = base < CAP ? base : CAP;
}

// ---------------- econtract body ----------------
__device__ __forceinline__ void econ_dev(float (*eL)[28],
                                         const float* __restrict__ pts,
                                         const float* __restrict__ feat,
                                         const int* __restrict__ pidx,
                                         const int* __restrict__ pcnt,
                                         u16* __restrict__ Shi, u16* __restrict__ Slo,
                                         int N, int Cin, int K, int Kpad, int mbase,
                                         int blockX) {
  const int g = mbase + blockX;
  const int b = g / N;
  const int t = threadIdx.x;
  const int w = t >> 6, lane = t & 63;
  const bool cact = t < Cin;
  const float px = pts[(size_t)g * 3 + 0];
  const float py = pts[(size_t)g * 3 + 1];
  const float pz = pts[(size_t)g * 3 + 2];
  float sxc = 0.f, syc = 0.f, szc = 0.f, cst = 0.f;
  if (lane < 27) {
    int a = lane / 9, bb = (lane / 3) % 3, cc = lane % 3;
    sxc = (a == 0) ? 64.f : ((a == 2) ? -64.f : 0.f);
    syc = (bb == 0) ? 64.f : ((bb == 2) ? -64.f : 0.f);
    szc = (cc == 0) ? 64.f : ((cc == 2) ? -64.f : 0.f);
    cst = -2.f * (float)((a != 1) + (bb != 1) + (cc != 1));
  }
  float acc[27];
#pragma unroll
  for (int l = 0; l < 27; ++l) acc[l] = 0.f;
  const int n = pcnt[g];
  const int* row = pidx + (size_t)g * CAP;
  for (int p = 0; p < n; ++p) {
    int j = row[p];
    size_t jb = (size_t)b * N + j;
    float dx = px - pts[jb * 3 + 0];
    float dy = py - pts[jb * 3 + 1];
    float dz = pz - pts[jb * 3 + 2];
    float d2 = dx * dx + dy * dy + dz * dz;
    if (lane < 27) {
      float ex = fmaf(-512.f, d2, fmaf(sxc, dx, fmaf(syc, dy, fmaf(szc, dz, cst))));
      eL[w][lane] = __expf(ex);
    }
    asm volatile("s_waitcnt lgkmcnt(0)" ::: "memory");
    __builtin_amdgcn_sched_barrier(0);
    float fv = cact ? feat[jb * Cin + t] : 0.f;
#pragma unroll
    for (int l = 0; l < 27; ++l) acc[l] = fmaf(eL[w][l], fv, acc[l]);
  }
  size_t rowo = (size_t)blockX * Kpad;
  if (cact) {
#pragma unroll
    for (int l = 0; l < 27; ++l) {
      float v = acc[l];
      u16 h = f2bf(v);
      u16 lo = f2bf(v - bf2f(h));
      Shi[rowo + (size_t)l * Cin + t] = h;
      Slo[rowo + (size_t)l * Cin + t] = lo;
    }
  }
  if (Kpad > K && t >= Cin && t < Cin + (Kpad - K)) {
    size_t po = rowo + K + (t - Cin);
    Shi[po] = 0; Slo[po] = 0;
  }
}

__global__ void k_econtract(const float* __restrict__ pts, const float* __restrict__ feat,
                            const int* __restrict__ pidx, const int* __restrict__ pcnt,
                            u16* __restrict__ Shi, u16* __restrict__ Slo,
                            int N, int Cin, int K, int Kpad, int mbase) {
  __shared__ float eL[4][28];
  econ_dev(eL, pts, feat, pidx, pcnt, Shi, Slo, N, Cin, K, Kpad, mbase, blockIdx.x);
}

// ---------------- fused econtract + FPS chunk (FIRST B blocks run FPS) ----------------
__global__ __launch_bounds__(64, 1) void k_econtract_fps(
    const float* __restrict__ pts, const float* __restrict__ feat,
    const int* __restrict__ pidx, const int* __restrict__ pcnt,
    u16* __restrict__ Shi, u16* __restrict__ Slo,
    int N, int Cin, int K, int Kpad, int mbase,
    int fpsMode, const float* __restrict__ fpsPts, float* __restrict__ fpsCenters, int fpsM,
    int it0, int it1, float* __restrict__ fpsD) {
  __shared__ float eL[4][28];
  if ((int)blockIdx.x < B) {
    fps_run(fpsMode, fpsPts, fpsCenters, fpsM, blockIdx.x, threadIdx.x, it0, it1, fpsD);
    return;
  }
  econ_dev(eL, pts, feat, pidx, pcnt, Shi, Slo, N, Cin, K, Kpad, mbase, blockIdx.x - B);
}

// ---------------- stage 2: MFMA GEMM (clean) ----------------
__global__ __launch_bounds__(512) void k_gemm_mfma(const u16* __restrict__ Shi,
                                                   const u16* __restrict__ Slo,
                                                   const float* __restrict__ W,
                                                   const float* __restrict__ bias,
                                                   float* __restrict__ out,
                                                   float* __restrict__ P,
                                                   int K, int Kpad, int Cout, float scale,
                                                   int mcur) {
  __shared__ u16 As[2][2][32][40];
  __shared__ u16 Bs[2][2][64][40];
  __shared__ float xch[4][64][8];
  const int t = threadIdx.x;
  const int h = t >> 8;
  const int tl = t & 255;
  const int nb = blockIdx.x * 64;
  const int m0 = blockIdx.y * 32;
  const int l = t & 63, w = t >> 6;
  const int ks = w >> 2, wq = w & 3;
  const int wm = (wq >> 1) * 16, wn = (wq & 1) * 32;
  const int la = l & 15, lg = l >> 4;
  const int ntiles = Kpad >> 6;
  const int KZ = gridDim.z, z = blockIdx.z;
  const int q = ntiles / KZ, r = ntiles % KZ;
  const int t0 = z * q + (z < r ? z : r);
  const int cnt = q + (z < r ? 1 : 0);
  const int ar = tl >> 3, ak = (tl & 7) * 4;
  const size_t aOff = (size_t)(m0 + ar) * Kpad + h * 32 + ak;
  const int aw = swk2(ar, ak);
  const int kp = (tl >> 4) * 2, n4 = (tl & 15) * 4;
  f32x4 acc0 = {0.f, 0.f, 0.f, 0.f}, acc1 = {0.f, 0.f, 0.f, 0.f};

  for (int kt = 0; kt < cnt; ++kt) {
    const int k0 = (t0 + kt) * 64;
    *(ushort4*)&As[h][0][ar][aw] = *(const ushort4*)(Shi + aOff + k0);
    *(ushort4*)&As[h][1][ar][aw] = *(const ushort4*)(Slo + aOff + k0);
    {
      int gk0 = k0 + h * 32 + kp;
      float4 b0 = make_float4(0.f, 0.f, 0.f, 0.f), b1 = b0;
      if (gk0 < K) b0 = *(const float4*)(W + (size_t)gk0 * Cout + nb + n4);
      if (gk0 + 1 < K) b1 = *(const float4*)(W + (size_t)(gk0 + 1) * Cout + nb + n4);
      float v0[4] = {b0.x, b0.y, b0.z, b0.w};
      float v1[4] = {b1.x, b1.y, b1.z, b1.w};
#pragma unroll
      for (int e = 0; e < 4; ++e) {
        int n = n4 + e;
        int kw = swk2(n, kp);
        u16 h0 = f2bf(v0[e]);
        u16 l0 = f2bf(v0[e] - bf2f(h0));
        u16 h1 = f2bf(v1[e]);
        u16 l1 = f2bf(v1[e] - bf2f(h1));
        *(unsigned*)&Bs[h][0][n][kw] = (unsigned)h0 | ((unsigned)h1 << 16);
        *(unsigned*)&Bs[h][1][n][kw] = (unsigned)l0 | ((unsigned)l1 << 16);
      }
    }
    __syncthreads();
    bf16x8 ah = *(const bf16x8*)&As[ks][0][wm + la][swk2(wm + la, lg * 8)];
    bf16x8 al = *(const bf16x8*)&As[ks][1][wm + la][swk2(wm + la, lg * 8)];
    bf16x8 bh0 = *(const bf16x8*)&Bs[ks][0][wn + la][swk2(wn + la, lg * 8)];
    bf16x8 bl0 = *(const bf16x8*)&Bs[ks][1][wn + la][swk2(wn + la, lg * 8)];
    bf16x8 bh1 = *(const bf16x8*)&Bs[ks][0][wn + 16 + la][swk2(wn + 16 + la, lg * 8)];
    bf16x8 bl1 = *(const bf16x8*)&Bs[ks][1][wn + 16 + la][swk2(wn + 16 + la, lg * 8)];
    acc0 = __builtin_amdgcn_mfma_f32_16x16x32_bf16(ah, bh0, acc0, 0, 0, 0);
    acc1 = __builtin_amdgcn_mfma_f32_16x16x32_bf16(ah, bh1, acc1, 0, 0, 0);
    acc0 = __builtin_amdgcn_mfma_f32_16x16x32_bf16(al, bh0, acc0, 0, 0, 0);
    acc1 = __builtin_amdgcn_mfma_f32_16x16x32_bf16(al, bh1, acc1, 0, 0, 0);
    acc0 = __builtin_amdgcn_mfma_f32_16x16x32_bf16(ah, bl0, acc0, 0, 0, 0);
    acc1 = __builtin_amdgcn_mfma_f32_16x16x32_bf16(ah, bl1, acc1, 0, 0, 0);
    __syncthreads();
  }
  if (w >= 4) {
#pragma unroll
    for (int r2 = 0; r2 < 4; ++r2) { xch[wq][l][r2] = acc0[r2]; xch[wq][l][r2 + 4] = acc1[r2]; }
  }
  __syncthreads();
  if (w < 4) {
#pragma unroll
    for (int r2 = 0; r2 < 4; ++r2) { acc0[r2] += xch[wq][l][r2]; acc1[r2] += xch[wq][l][r2 + 4]; }
    if (gridDim.z == 1) {
#pragma unroll
      for (int r2 = 0; r2 < 4; ++r2) {
        int gm = m0 + wm + lg * 4 + r2;
        int gn0 = nb + wn + la;
        out[(size_t)gm * Cout + gn0] = fmaxf(fmaf(acc0[r2], scale, bias[gn0]), 0.f);
        int gn1 = gn0 + 16;
        out[(size_t)gm * Cout + gn1] = fmaxf(fmaf(acc1[r2], scale, bias[gn1]), 0.f);
      }
    } else {
      float* Pz = P + (size_t)z * mcur * Cout;
#pragma unroll
      for (int r2 = 0; r2 < 4; ++r2) {
        int gm = m0 + wm + lg * 4 + r2;
        int gn0 = nb + wn + la;
        Pz[(size_t)gm * Cout + gn0] = acc0[r2];
        Pz[(size_t)gm * Cout + gn0 + 16] = acc1[r2];
      }
    }
  }
}

// ---------------- split-K reduce ----------------
__global__ __launch_bounds__(256) void k_reduce(const float* __restrict__ P,
                                                const float* __restrict__ bias,
                                                float* __restrict__ out,
                                                int n4, int Cout, int KZ, float scale,
                                                int stride) {
  int i = blockIdx.x * 256 + threadIdx.x;
  if (i >= n4) return;
  float4 s = *(const float4*)(P + (size_t)i * 4);
  for (int z = 1; z < KZ; ++z) {
    float4 v = *(const float4*)(P + (size_t)z * stride + (size_t)i * 4);
    s.x += v.x; s.y += v.y; s.z += v.z; s.w += v.w;
  }
  int c = (i * 4) % Cout;
  float4 bb = *(const float4*)(bias + c);
  float4 o;
  o.x = fmaxf(fmaf(s.x, scale, bb.x), 0.f);
  o.y = fmaxf(fmaf(s.y, scale, bb.y), 0.f);
  o.z = fmaxf(fmaf(s.z, scale, bb.z), 0.f);
  o.w = fmaxf(fmaf(s.w, scale, bb.w), 0.f);
  *(float4*)(out + (size_t)i * 4) = o;
}

// level-2 (m=1): center = first point; init assign=0
__global__ __launch_bounds__(64) void k_center0(const float* __restrict__ pts,
                                                float* __restrict__ centers,
                                                int* __restrict__ assign) {
  const int b = blockIdx.x, t = threadIdx.x;
  if (t < 3) centers[b * 3 + t] = pts[(size_t)b * 64 * 3 + t];
  assign[b * 64 + t] = 0;
}

// ---------------- assignment ----------------
__global__ __launch_bounds__(256) void k_assign(const float* __restrict__ pts,
                                                const float* __restrict__ centers,
                                                int* __restrict__ assign, int N, int m) {
  __shared__ float cs[256 * 3];
  const int t = threadIdx.x;
  const int idx = blockIdx.x * 256 + t;
  const int b = (blockIdx.x * 256) / N;
  for (int i = t; i < m * 3; i += 256) cs[i] = centers[(size_t)b * m * 3 + i];
  __syncthreads();
  float px = pts[(size_t)idx * 3 + 0], py = pts[(size_t)idx * 3 + 1], pz = pts[(size_t)idx * 3 + 2];
  float best = 3.4e38f; int bk = 0;
  for (int k = 0; k < m; ++k) {
    float dx = __fsub_rn(px, cs[k * 3 + 0]);
    float dy = __fsub_rn(py, cs[k * 3 + 1]);
    float dz = __fsub_rn(pz, cs[k * 3 + 2]);
    float dd = __fadd_rn(__fadd_rn(__fmul_rn(dx, dx), __fmul_rn(dy, dy)), __fmul_rn(dz, dz));
    if (dd < best) { best = dd; bk = k; }
  }
  assign[idx] = bk;
}

// segment max via int atomicMax
__global__ __launch_bounds__(256) void k_segmax(const float* __restrict__ feat,
                                                const int* __restrict__ assign,
                                                float* __restrict__ pooled,
                                                int N, int m, int C) {
  int idx = blockIdx.x * blockDim.x + threadIdx.x;
  if (idx >= B * N * C) return;
  int b = idx / (N * C);
  int r = idx - b * N * C;
  int i = r / C;
  int c = r - i * C;
  int a = assign[b * N + i];
  atomicMax((int*)&pooled[((size_t)b * m + a) * C + c], __float_as_int(feat[idx]));
}

// ---------------- FC ----------------
template <int K, int COUT, bool BNR>
__global__ __launch_bounds__(256) void k_fc(const float* __restrict__ x,
                                            const float* __restrict__ w,
                                            const float* __restrict__ g,
                                            const float* __restrict__ be,
                                            float* __restrict__ out) {
  __shared__ float ys[8][33];
  int t = threadIdx.x;
  int n = t >> 5, cl = t & 31;
  int c = blockIdx.x * 32 + cl;
  float acc = 0.f;
  if (c < COUT) {
    const float* xr = x + n * K;
    float a0 = 0.f, a1 = 0.f, a2 = 0.f, a3 = 0.f;
    for (int k = 0; k < K; k += 4) {
      a0 = fmaf(xr[k + 0], w[(size_t)(k + 0) * COUT + c], a0);
      a1 = fmaf(xr[k + 1], w[(size_t)(k + 1) * COUT + c], a1);
      a2 = fmaf(xr[k + 2], w[(size_t)(k + 2) * COUT + c], a2);
      a3 = fmaf(xr[k + 3], w[(size_t)(k + 3) * COUT + c], a3);
    }
    acc = (a0 + a1) + (a2 + a3);
  }
  ys[n][cl] = acc;
  __syncthreads();
  if (c >= COUT) return;
  if (BNR) {
    float mu = 0.f;
#pragma unroll
    for (int q = 0; q < 8; ++q) mu += ys[q][cl];
    mu *= 0.125f;
    float var = 0.f;
#pragma unroll
    for (int q = 0; q < 8; ++q) { float dv = ys[q][cl] - mu; var = fmaf(dv, dv, var); }
    var *= 0.125f;
    float rs = 1.f / sqrtf(var + 1e-5f);
    float v = g[c] * (acc - mu) * rs + be[c];
    out[n * COUT + c] = fmaxf(v, 0.f);
  } else {
    out[n * COUT + c] = acc + be[c];
  }
}

// ---------------- launcher ----------------
extern "C" void kernel_launch(void* const* d_in, const int* in_sizes, int n_in,
                              void* d_out, int out_size, void* d_ws, size_t ws_size,
                              hipStream_t stream) {
  (void)in_sizes; (void)n_in; (void)out_size;
  const float* pc = (const float*)d_in[0];
  const float* Wc[6]; const float* bc[6];
  for (int l = 0; l < 6; ++l) { Wc[l] = (const float*)d_in[1 + 2 * l]; bc[l] = (const float*)d_in[2 + 2 * l]; }
  const float* w1 = (const float*)d_in[13];
  const float* g1 = (const float*)d_in[14];
  const float* be1 = (const float*)d_in[15];
  const float* w2 = (const float*)d_in[16];
  const float* g2 = (const float*)d_in[17];
  const float* be2 = (const float*)d_in[18];
  const float* w3 = (const float*)d_in[19];
  const float* b3 = (const float*)d_in[20];

  float* ws = (float*)d_ws;
  size_t o = 0;
  auto A = [&](size_t n) { size_t r = o; o += (n + 63) & ~(size_t)63; return r; };
  const size_t PTS0 = A((size_t)B * 1024 * 3);
  const size_t PTS1 = A((size_t)B * 256 * 3);
  const size_t PTS2 = A((size_t)B * 64 * 3);
  const size_t PTS3 = A((size_t)B * 3);
  const size_t F0  = A((size_t)B * 1024 * 4);
  const size_t FB1 = A((size_t)B * 1024 * 64);
  const size_t FB2 = A((size_t)B * 1024 * 64);
  const size_t FB3 = A((size_t)B * 256 * 64);
  const size_t FB4 = A((size_t)B * 256 * 128);
  const size_t FB5 = A((size_t)B * 256 * 128);
  const size_t FB6 = A((size_t)B * 64 * 128);
  const size_t FB7 = A((size_t)B * 64 * 256);
  const size_t FB8 = A((size_t)B * 64 * 1024);
  const size_t FB9 = A((size_t)B * 1024);
  const size_t ASSIGN = A((size_t)B * 1024);
  const size_t Y1 = A((size_t)8 * 512);
  const size_t Y2 = A((size_t)8 * 256);
  const size_t FPSD = A((size_t)B * 1024);
  const size_t PIDX = A((size_t)B * 1024 * CAP);
  const size_t PCNT = A((size_t)B * 1024);
  const size_t dynB = o * sizeof(float);

  int* pidx = (int*)(ws + PIDX);
  int* pcnt = (int*)(ws + PCNT);

  // prep hosts fps1024 chunk [1,65) reading pc directly
  k_prep<<<dim3(B + (B * N0 + 255) / 256), dim3(256), 0, stream>>>(
      pc, ws + PTS0, ws + F0,
      (uint4*)(ws + FB3), B * 256 * 64 / 4,
      (uint4*)(ws + FB6), B * 64 * 128 / 4,
      (uint4*)(ws + FB9), B * 1024 / 4,
      ws + PTS1, ws + FPSD);

  auto conv = [&](size_t ptsOff, size_t finOff, size_t foutOff, int Npts, int Cin, int Cout,
                  const float* W, const float* bias,
                  int fpsMode, size_t fpsPtsOff, size_t fpsCtrOff, int fpsM,
                  int eIt0, int eIt1) {
    const int M = B * Npts;
    const int K = 27 * Cin;
    const int Kpad = (K + 63) & ~63;
    const size_t availB = (ws_size > dynB) ? ws_size - dynB : 0;
    size_t pResB = availB / 4;
    if (pResB > (size_t)13 << 20) pResB = (size_t)13 << 20;
    const size_t sByte = availB - pResB;
    long mc = (long)(sByte / ((size_t)Kpad * 4)) & ~31L;
    int Mc = (int)((mc < (long)M) ? mc : (long)M);
    if (Mc < 32) Mc = 32;
    u16* Shi = (u16*)((char*)d_ws + dynB);
    u16* Slo = Shi + (size_t)Mc * Kpad;
    float* P = (float*)(Shi + (size_t)2 * Mc * Kpad);
    const int mch = (M + Mc - 1) / Mc;
    const float scale = 1.f / (float)Npts;
    const int blk = (Cin <= 64) ? 64 : Cin;
    const int ntiles = Kpad >> 6;
    for (int mcb = 0; mcb < mch; ++mcb) {
      const int mb0 = mcb * Mc;
      const int mcur = ((M - mb0) < Mc) ? (M - mb0) : Mc;
      if (mcb == 0 && fpsMode && blk == 64) {
        k_econtract_fps<<<dim3(mcur + B), dim3(64), 0, stream>>>(
            ws + ptsOff, ws + finOff, pidx, pcnt, Shi, Slo, Npts, Cin, K, Kpad, mb0,
            fpsMode, ws + fpsPtsOff, ws + fpsCtrOff, fpsM, eIt0, eIt1, ws + FPSD);
      } else {
        k_econtract<<<dim3(mcur), dim3(blk), 0, stream>>>(ws + ptsOff, ws + finOff, pidx, pcnt,
                                                          Shi, Slo, Npts, Cin, K, Kpad, mb0);
      }
      const int gx = Cout / 64, gy = mcur / 32;
      int kz = 1024 / (gx * gy);
      if (kz < 1) kz = 1;
      if (kz > ntiles) kz = ntiles;
      if (kz > 16) kz = 16;
      long pcap = (long)(pResB / ((size_t)mcur * Cout * 4));
      if ((long)kz > pcap) kz = (pcap < 1) ? 1 : (int)pcap;
      float* outp = ws + foutOff + (size_t)mb0 * Cout;
      k_gemm_mfma<<<dim3(gx, gy, kz), dim3(512), 0, stream>>>(
          Shi, Slo, W, bias, outp, P, K, Kpad, Cout, scale, mcur);
      if (kz > 1) {
        int n4 = mcur * Cout / 4;
        k_reduce<<<dim3((n4 + 255) / 256), dim3(256), 0, stream>>>(
            P, bias, outp, n4, Cout, kz, scale, mcur * Cout);
      }
    }
  };

  // ---- level 0: fps1024 chunks [1,65) prep | [65,129) pairs | [129,193) conv1 | [193,256) conv2 ----
  k_pairs_f<<<dim3(B + B * 1024 / 4), dim3(256), 0, stream>>>(
      ws + PTS0, pidx, pcnt, 1024, 1, ws + PTS0, ws + PTS1, 256, 65, 129, ws + FPSD);
  conv(PTS0, F0, FB1, 1024, 4, 64, Wc[0], bc[0], 1, PTS0, PTS1, 256, 129, 193);
  conv(PTS0, FB1, FB2, 1024, 64, 64, Wc[1], bc[1], 1, PTS0, PTS1, 256, 193, 256);
  k_assign<<<dim3(B * 1024 / 256), dim3(256), 0, stream>>>(ws + PTS0, ws + PTS1, (int*)(ws + ASSIGN), 1024, 256);
  k_segmax<<<dim3((B * 1024 * 64 + 255) / 256), dim3(256), 0, stream>>>(ws + FB2, (int*)(ws + ASSIGN), ws + FB3, 1024, 256, 64);
  // ---- level 1: fps256 chunks [1,33) pairs | [33,64) conv3 ----
  k_pairs_f<<<dim3(B + B * 256 / 4), dim3(256), 0, stream>>>(
      ws + PTS1, pidx, pcnt, 256, 2, ws + PTS1, ws + PTS2, 64, 1, 33, ws + FPSD);
  conv(PTS1, FB3, FB4, 256, 64, 128, Wc[2], bc[2], 2, PTS1, PTS2, 64, 33, 64);
  conv(PTS1, FB4, FB5, 256, 128, 128, Wc[3], bc[3], 0, 0, 0, 0, 0, 0);
  k_assign<<<dim3(B * 256 / 256), dim3(256), 0, stream>>>(ws + PTS1, ws + PTS2, (int*)(ws + ASSIGN), 256, 64);
  k_segmax<<<dim3((B * 256 * 128 + 255) / 256), dim3(256), 0, stream>>>(ws + FB5, (int*)(ws + ASSIGN), ws + FB6, 256, 64, 128);
  // ---- level 2 ----
  k_pairs_f<<<dim3(B * 64 / 4), dim3(256), 0, stream>>>(
      ws + PTS2, pidx, pcnt, 64, 0, nullptr, nullptr, 0, 0, 0, nullptr);
  conv(PTS2, FB6, FB7, 64, 128, 256, Wc[4], bc[4], 0, 0, 0, 0, 0, 0);
  conv(PTS2, FB7, FB8, 64, 256, 1024, Wc[5], bc[5], 0, 0, 0, 0, 0, 0);
  k_center0<<<dim3(B), dim3(64), 0, stream>>>(ws + PTS2, ws + PTS3, (int*)(ws + ASSIGN));
  k_segmax<<<dim3((B * 64 * 1024 + 255) / 256), dim3(256), 0, stream>>>(ws + FB8, (int*)(ws + ASSIGN), ws + FB9, 64, 1, 1024);
  // ---- FC head ----
  k_fc<1024, 512, true><<<dim3(512 / 32), dim3(256), 0, stream>>>(ws + FB9, w1, g1, be1, ws + Y1);
  k_fc<512, 256, true><<<dim3(256 / 32), dim3(256), 0, stream>>>(ws + Y1, w2, g2, be2, ws + Y2);
  k_fc<256, 40, false><<<dim3(2), dim3(256), 0, stream>>>(ws + Y2, w3, nullptr, b3, (float*)d_out);
}